// Round 1
// baseline (767.330 us; speedup 1.0000x reference)
//
#include <hip/hip_runtime.h>
#include <hip/hip_bf16.h>

// Problem constants
#define N_ROWS 8192
#define DIM    2048
#define NCLS   751
#define NPAD   768     // wc padded rows (6*128)
#define KNN    6       // K+1 neighbors (incl self)
#define NCAND  12      // rescore candidates (gap(6,12) >> bf16 quant error)
#define GAP_THRESH 1.25e-3f   // bf16 rank-6/7 gap above which top-6 set is exact

typedef __attribute__((ext_vector_type(8))) short bf16x8;
typedef __attribute__((ext_vector_type(4))) float f32x4;

// ---------------------------------------------------------------------------
// async global->LDS, 16B per lane. LDS dest must be wave-uniform base + lane*16.
__device__ __forceinline__ void async_ld16(const __hip_bfloat16* g, __hip_bfloat16* l) {
    __builtin_amdgcn_global_load_lds(
        (__attribute__((address_space(1))) void*)(g),
        (__attribute__((address_space(3))) void*)(l), 16, 0, 0);
}

__device__ __forceinline__ float bf16_to_f32(short s) {
    union { float f; unsigned u; } cv;
    cv.u = ((unsigned)(unsigned short)s) << 16;
    return cv.f;
}

// ---------------------------------------------------------------------------
// Row L2 norms (f64-accurate) + bf16 normalized rows for the similarity GEMM.
__global__ void normalize_kernel(const float* __restrict__ x,
                                 __hip_bfloat16* __restrict__ xnb,
                                 double* __restrict__ invnorm) {
    int row = blockIdx.x, tid = threadIdx.x;   // 256 threads
    const float4* xr4 = (const float4*)(x + (size_t)row * DIM);
    float4 v0 = xr4[tid], v1 = xr4[tid + 256];
    double s = (double)v0.x * v0.x + (double)v0.y * v0.y +
               (double)v0.z * v0.z + (double)v0.w * v0.w +
               (double)v1.x * v1.x + (double)v1.y * v1.y +
               (double)v1.z * v1.z + (double)v1.w * v1.w;
    __shared__ double red[256];
    red[tid] = s; __syncthreads();
    for (int off = 128; off; off >>= 1) {
        if (tid < off) red[tid] += red[tid + off];
        __syncthreads();
    }
    double norm = sqrt(red[0]);
    if (norm < 1e-12) norm = 1e-12;
    double inv = 1.0 / norm;
    if (tid == 0) invnorm[row] = inv;
    float invf = (float)inv;
    __hip_bfloat16* o0 = xnb + (size_t)row * DIM + tid * 4;
    o0[0] = __float2bfloat16(v0.x * invf);
    o0[1] = __float2bfloat16(v0.y * invf);
    o0[2] = __float2bfloat16(v0.z * invf);
    o0[3] = __float2bfloat16(v0.w * invf);
    __hip_bfloat16* o1 = o0 + 1024;
    o1[0] = __float2bfloat16(v1.x * invf);
    o1[1] = __float2bfloat16(v1.y * invf);
    o1[2] = __float2bfloat16(v1.z * invf);
    o1[3] = __float2bfloat16(v1.w * invf);
}

// ---------------------------------------------------------------------------
// Triangular symmetric GEMM: S = A A^T.
// R6: 256x256 tile, 8 waves (2Mx4N, per-wave 128x64 out), BK=32,
// TRIPLE-buffered LDS (3 x 32KB = 96KB) deep pipeline:
//   - staging for tile kt+2 is issued into buf[(kt+2)%3] while computing
//     buf[kt%3] -> no overwrite race by construction (reads of that buffer's
//     old tile finished last iteration, before its closing barrier).
//   - counted s_waitcnt vmcnt(4) at iteration close (1 K-tile = 4 loads/thread
//     in flight, never drained to 0 in steady state; loads get ~1.5 iterations
//     of slack, covering L2/L3 latency -- input is 32MB, L3-resident).
//   - 2 phases per K-tile, each {8/4 ds_read_b128; 2 global_load_lds; raw
//     s_barrier; lgkmcnt(0); setprio(1); 16 MFMA; setprio(0); barrier} --
//     same phase density as the verified 8-phase 256^2 template.
// XOR k-chunk swizzle (slot = quad ^ ((row>>1)&3)) carried over unchanged
// from the harness-verified 128^2 version -> S output is bit-identical.
__global__ __launch_bounds__(512, 2)
void gemm_syrk(const __hip_bfloat16* __restrict__ A,
               __hip_bfloat16* __restrict__ S) {
    __shared__ __align__(16) char smem[3 * 32768];   // 96 KB

    // decode upper-triangle tile (bi <= bj) from linear block id (32x32 tiles)
    int b = blockIdx.x;
    int bi = (int)((65.0 - sqrt(4225.0 - 8.0 * (double)b)) * 0.5);
    while (32 * (bi + 1) - (bi + 1) * bi / 2 <= b) ++bi;
    while (bi > 0 && 32 * bi - bi * (bi - 1) / 2 > b) --bi;
    int bj = bi + b - (32 * bi - bi * (bi - 1) / 2);
    const size_t bm = (size_t)bi * 256, bn = (size_t)bj * 256;

    const int tid  = threadIdx.x;                // 512 threads = 8 waves
    const int wave = tid >> 6, lane = tid & 63;
    const int wm = (wave >> 2) * 128;            // A-row half of this wave
    const int wn = (wave & 3) * 64;              // B-row (=col) quarter
    const int quad = lane >> 4, l15 = lane & 15;

    // staging chunk maps: chunk c (0..1023) -> row r = c>>2, slot c&3,
    // global k-chunk = ((c&3) ^ ((r>>1)&3)) * 8   (inverse of read swizzle)
    const int c0 = tid,       r0 = c0 >> 2, g0 = ((c0 & 3) ^ ((r0 >> 1) & 3)) * 8;
    const int c1 = tid + 512, r1 = c1 >> 2, g1 = ((c1 & 3) ^ ((r1 >> 1) & 3)) * 8;

    const __hip_bfloat16* gA0 = A + (bm + r0) * (size_t)DIM + g0;
    const __hip_bfloat16* gA1 = A + (bm + r1) * (size_t)DIM + g1;
    const __hip_bfloat16* gB0 = A + (bn + r0) * (size_t)DIM + g0;
    const __hip_bfloat16* gB1 = A + (bn + r1) * (size_t)DIM + g1;

    auto Abuf = [&](int bf) { return (__hip_bfloat16*)(smem + bf * 32768); };
    auto Bbuf = [&](int bf) { return (__hip_bfloat16*)(smem + bf * 32768 + 16384); };

    f32x4 acc[8][4];
#pragma unroll
    for (int mi = 0; mi < 8; ++mi)
#pragma unroll
        for (int ni = 0; ni < 4; ++ni)
            acc[mi][ni] = (f32x4){0.f, 0.f, 0.f, 0.f};

    const int KT = DIM / 32;                     // 64 K-tiles

    // prologue: stage tiles 0 and 1; drain tile 0 (counted), barrier
    async_ld16(gA0,      Abuf(0) + c0 * 8);
    async_ld16(gA1,      Abuf(0) + c1 * 8);
    async_ld16(gB0,      Bbuf(0) + c0 * 8);
    async_ld16(gB1,      Bbuf(0) + c1 * 8);
    async_ld16(gA0 + 32, Abuf(1) + c0 * 8);
    async_ld16(gA1 + 32, Abuf(1) + c1 * 8);
    async_ld16(gB0 + 32, Bbuf(1) + c0 * 8);
    async_ld16(gB1 + 32, Bbuf(1) + c1 * 8);
    asm volatile("s_waitcnt vmcnt(4)" ::: "memory");
    __builtin_amdgcn_s_barrier();

    int cur = 0;
    for (int kt = 0; kt < KT; ++kt) {
        const int nxt = (cur + 2 >= 3) ? cur - 1 : cur + 2;
        __hip_bfloat16* As = Abuf(cur);
        __hip_bfloat16* Bs = Bbuf(cur);
        const bool st = (kt < KT - 2);
        const int kb = (kt + 2) << 5;

        // ---- phase 0: B frags (all ni) + A frags mi 0..3; stage A of kt+2
        bf16x8 bfr[4], af[4];
#pragma unroll
        for (int ni = 0; ni < 4; ++ni) {
            int rr = wn + ni * 16 + l15;
            bfr[ni] = *(const bf16x8*)&Bs[(rr * 4 + (quad ^ ((rr >> 1) & 3))) * 8];
        }
#pragma unroll
        for (int mi = 0; mi < 4; ++mi) {
            int rr = wm + mi * 16 + l15;
            af[mi] = *(const bf16x8*)&As[(rr * 4 + (quad ^ ((rr >> 1) & 3))) * 8];
        }
        if (st) {
            async_ld16(gA0 + kb, Abuf(nxt) + c0 * 8);
            async_ld16(gA1 + kb, Abuf(nxt) + c1 * 8);
        }
        __builtin_amdgcn_s_barrier();
        asm volatile("s_waitcnt lgkmcnt(0)" ::: "memory");
        __builtin_amdgcn_sched_barrier(0);
        __builtin_amdgcn_s_setprio(1);
#pragma unroll
        for (int mi = 0; mi < 4; ++mi)
#pragma unroll
            for (int ni = 0; ni < 4; ++ni)
                acc[mi][ni] = __builtin_amdgcn_mfma_f32_16x16x32_bf16(
                    af[mi], bfr[ni], acc[mi][ni], 0, 0, 0);
        __builtin_amdgcn_s_setprio(0);
        __builtin_amdgcn_s_barrier();

        // ---- phase 1: A frags mi 4..7; stage B of kt+2
#pragma unroll
        for (int mi = 0; mi < 4; ++mi) {
            int rr = wm + (mi + 4) * 16 + l15;
            af[mi] = *(const bf16x8*)&As[(rr * 4 + (quad ^ ((rr >> 1) & 3))) * 8];
        }
        if (st) {
            async_ld16(gB0 + kb, Bbuf(nxt) + c0 * 8);
            async_ld16(gB1 + kb, Bbuf(nxt) + c1 * 8);
        }
        __builtin_amdgcn_s_barrier();
        asm volatile("s_waitcnt lgkmcnt(0)" ::: "memory");
        __builtin_amdgcn_sched_barrier(0);
        __builtin_amdgcn_s_setprio(1);
#pragma unroll
        for (int mi = 0; mi < 4; ++mi)
#pragma unroll
            for (int ni = 0; ni < 4; ++ni)
                acc[mi + 4][ni] = __builtin_amdgcn_mfma_f32_16x16x32_bf16(
                    af[mi], bfr[ni], acc[mi + 4][ni], 0, 0, 0);
        __builtin_amdgcn_s_setprio(0);

        // ---- iteration close: counted drain of tile kt+1 (4 loads of kt+2
        //      remain in flight); never vmcnt(0) until the tail.
        if (st) { asm volatile("s_waitcnt vmcnt(4)" ::: "memory"); }
        else    { asm volatile("s_waitcnt vmcnt(0)" ::: "memory"); }
        __builtin_amdgcn_s_barrier();

        cur = (cur + 1 == 3) ? 0 : cur + 1;
    }

    // direct store (C/D layout: col=lane&15, row=quad*4+e)
#pragma unroll
    for (int mi = 0; mi < 8; ++mi)
#pragma unroll
        for (int ni = 0; ni < 4; ++ni)
#pragma unroll
            for (int e = 0; e < 4; ++e) {
                size_t row = bm + wm + mi * 16 + quad * 4 + e;
                size_t col = bn + wn + ni * 16 + l15;
                S[row * N_ROWS + col] = __float2bfloat16(acc[mi][ni][e]);
            }

    if (bi != bj) {
        // transposed tile via LDS (8 passes of 32 cols), vector stores.
        // T is 32 x 264 bf16 (stride 264: 16B-aligned rows, non-pow2 banks).
        __hip_bfloat16* T = (__hip_bfloat16*)smem;
#pragma unroll
        for (int p = 0; p < 8; ++p) {
            __syncthreads();
            if ((wave & 3) == (p >> 1)) {        // the 2 waves owning this col range
#pragma unroll
                for (int nio = 0; nio < 2; ++nio) {
                    int ni = (p & 1) * 2 + nio;
                    int tc = ni * 16 + l15 - (p & 1) * 32;   // 0..31
#pragma unroll
                    for (int mi = 0; mi < 8; ++mi)
#pragma unroll
                        for (int e = 0; e < 4; ++e) {
                            int r = wm + mi * 16 + quad * 4 + e;
                            T[tc * 264 + r] = __float2bfloat16(acc[mi][ni][e]);
                        }
                }
            }
            __syncthreads();
#pragma unroll
            for (int j2 = 0; j2 < 2; ++j2) {
                int q = tid + 512 * j2;           // 0..1023
                int tc = q >> 5, r8 = (q & 31) * 8;
                *(bf16x8*)&S[(bn + p * 32 + tc) * N_ROWS + bm + r8] =
                    *(const bf16x8*)&T[tc * 264 + r8];
            }
        }
    }
}

// ---------------------------------------------------------------------------
// Generic NT bf16 GEMM, BK=64 (R3-measured best for these grid-limited
// shapes: <=1024 blocks -> 4 blocks/CU, LDS cap 5, so 32 KB LDS is free and
// barrier drains halve). XOR-swizzled LDS: chunk slot = gchunk ^ (row&7).
// C[M,N] = A[M,K] * B[N,K]^T. TM = rows per block (128 or 64). EPI:
//   1 = relu(v+bias) -> bf16
//   4 = v+bias -> bf16, plus per-column sum/sumsq atomics into stats (BN)
//   5 = v+bias -> fp32, col<ncols guard (classifier with folded BN)
template <int EPI, int TM>
__global__ __launch_bounds__(256)
void gemm_nt(const __hip_bfloat16* __restrict__ A,
             const __hip_bfloat16* __restrict__ B,
             void* __restrict__ Cv,
             const float* __restrict__ bias,
             float* __restrict__ stats,
             int K, int ldc, int ncols) {
    constexpr int MI = TM / 32;                       // 4 or 2
    __shared__ __align__(16) char smem[TM * 128 + 16384];
    __hip_bfloat16* As = (__hip_bfloat16*)smem;                // TM x 64
    __hip_bfloat16* Bs = (__hip_bfloat16*)(smem + TM * 128);   // 128 x 64
    const int tid  = threadIdx.x;
    const size_t bm = (size_t)blockIdx.y * TM, bn = (size_t)blockIdx.x * 128;
    const int wave = tid >> 6, lane = tid & 63;
    const int wm = (wave & 1) * (TM / 2), wn = (wave >> 1) * 64;
    const int quad = lane >> 4, l15 = lane & 15;

    f32x4 acc[MI][4];
#pragma unroll
    for (int mi = 0; mi < MI; ++mi)
#pragma unroll
        for (int ni = 0; ni < 4; ++ni)
            acc[mi][ni] = (f32x4){0.f, 0.f, 0.f, 0.f};

    const int KT = K >> 6;
    for (int kt = 0; kt < KT; ++kt) {
        const int kb = kt << 6;
        __syncthreads();
#pragma unroll
        for (int j = 0; j < TM / 32; ++j) {
            int q = tid + 256 * j, r = q >> 3, g = ((q & 7) ^ (r & 7)) * 8;
            async_ld16(A + (bm + r) * (size_t)K + kb + g, As + q * 8);
        }
#pragma unroll
        for (int j = 0; j < 4; ++j) {
            int q = tid + 256 * j, r = q >> 3, g = ((q & 7) ^ (r & 7)) * 8;
            async_ld16(B + (bn + r) * (size_t)K + kb + g, Bs + q * 8);
        }
        __syncthreads();

#pragma unroll
        for (int s = 0; s < 2; ++s) {
            bf16x8 af[MI], bfr[4];
#pragma unroll
            for (int mi = 0; mi < MI; ++mi) {
                int rr = wm + mi * 16 + l15;
                af[mi] = *(const bf16x8*)&As[(rr * 8 + ((s * 4 + quad) ^ (rr & 7))) * 8];
            }
#pragma unroll
            for (int ni = 0; ni < 4; ++ni) {
                int rr = wn + ni * 16 + l15;
                bfr[ni] = *(const bf16x8*)&Bs[(rr * 8 + ((s * 4 + quad) ^ (rr & 7))) * 8];
            }
#pragma unroll
            for (int mi = 0; mi < MI; ++mi)
#pragma unroll
                for (int ni = 0; ni < 4; ++ni)
                    acc[mi][ni] = __builtin_amdgcn_mfma_f32_16x16x32_bf16(
                        af[mi], bfr[ni], acc[mi][ni], 0, 0, 0);
        }
    }

    float s1[4] = {0.f, 0.f, 0.f, 0.f}, s2[4] = {0.f, 0.f, 0.f, 0.f};
#pragma unroll
    for (int mi = 0; mi < MI; ++mi)
#pragma unroll
        for (int ni = 0; ni < 4; ++ni)
#pragma unroll
            for (int e = 0; e < 4; ++e) {
                size_t row = bm + wm + mi * 16 + quad * 4 + e;
                int col = (int)(bn + wn + ni * 16 + l15);
                float v = acc[mi][ni][e];
                if (EPI == 1) {
                    v += bias[col]; v = v > 0.f ? v : 0.f;
                    ((__hip_bfloat16*)Cv)[row * (size_t)ldc + col] = __float2bfloat16(v);
                } else if (EPI == 4) {
                    v += bias[col];
                    ((__hip_bfloat16*)Cv)[row * (size_t)ldc + col] = __float2bfloat16(v);
                    s1[ni] += v; s2[ni] += v * v;    // exact (pre-quantization) stats
                } else {
                    v += bias[col];
                    if (col < ncols)
                        ((float*)Cv)[row * (size_t)ldc + col] = v;
                }
            }

    if (EPI == 4) {
        // column sums: quad-butterfly, LDS merge over the two wm halves, atomics
        __syncthreads();                    // all waves done with As/Bs
        float* sred = (float*)smem;         // [2 halves][128 cols][2 stats]
#pragma unroll
        for (int ni = 0; ni < 4; ++ni) {
            float a = s1[ni], bq = s2[ni];
            a += __shfl_xor(a, 16);  a += __shfl_xor(a, 32);
            bq += __shfl_xor(bq, 16); bq += __shfl_xor(bq, 32);
            if (lane < 16) {
                int c = wn + ni * 16 + l15;
                sred[((wave & 1) * 128 + c) * 2 + 0] = a;
                sred[((wave & 1) * 128 + c) * 2 + 1] = bq;
            }
        }
        __syncthreads();
        if (tid < 128) {
            float ta = sred[tid * 2] + sred[(128 + tid) * 2];
            float tb = sred[tid * 2 + 1] + sred[(128 + tid) * 2 + 1];
            atomicAdd(&stats[bn + tid], ta);
            atomicAdd(&stats[DIM + bn + tid], tb);
        }
    }
}

// ---------------------------------------------------------------------------
// Per-row top-NCAND candidates from bf16 similarity row. 1 wave per row.
// Fast path: single compare vs running 6th-best; insert is rare (~6/t decay).
// Confident-row shortcut: if bf16 gap(rank6, rank7) >= GAP_THRESH, the bf16
// top-6 SET is provably the fp32 top-6 set -> write idx6 directly; else
// append row to the rescore worklist.
__global__ void topk_cand_kernel(const __hip_bfloat16* __restrict__ S,
                                 int* __restrict__ cand,
                                 int* __restrict__ idx6,
                                 int* __restrict__ wl,
                                 int* __restrict__ cnt) {
    int row = blockIdx.x, lane = threadIdx.x;   // 64 threads
    const bf16x8* Sr8 = (const bf16x8*)(S + (size_t)row * N_ROWS);
    float bv[6]; int bi6[6];
#pragma unroll
    for (int t = 0; t < 6; ++t) { bv[t] = -1e30f; bi6[t] = -1; }
    float vmin = -1e30f;
    for (int it = 0; it < N_ROWS / (64 * 8); ++it) {
        int c8 = it * 64 + lane;
        bf16x8 v8 = Sr8[c8];
#pragma unroll
        for (int u = 0; u < 8; ++u) {
            float v = bf16_to_f32(v8[u]);
            if (v > vmin) {
                int ms = 0; float mv = bv[0];
#pragma unroll
                for (int t = 1; t < 6; ++t) if (bv[t] < mv) { mv = bv[t]; ms = t; }
                bv[ms] = v; bi6[ms] = c8 * 8 + u;
                vmin = bv[0];
#pragma unroll
                for (int t = 1; t < 6; ++t) vmin = fminf(vmin, bv[t]);
            }
        }
    }
    __shared__ float sv[384];
    __shared__ int   si[384];
    __shared__ float topv[NCAND];
    __shared__ int   topi[NCAND];
#pragma unroll
    for (int t = 0; t < 6; ++t) { sv[lane * 6 + t] = bv[t]; si[lane * 6 + t] = bi6[t]; }
    __syncthreads();
    for (int t = 0; t < NCAND; ++t) {
        float m = -1e30f; int mpos = -1, midx = 0x7fffffff;
        for (int e = lane; e < 384; e += 64) {
            float v = sv[e]; int ix = si[e];
            if (v > m || (v == m && ix < midx)) { m = v; mpos = e; midx = ix; }
        }
#pragma unroll
        for (int off = 32; off; off >>= 1) {
            float ov = __shfl_xor(m, off);
            int   op = __shfl_xor(mpos, off);
            int   oi = __shfl_xor(midx, off);
            if (ov > m || (ov == m && oi < midx)) { m = ov; mpos = op; midx = oi; }
        }
        if (lane == 0) {
            cand[row * NCAND + t] = midx;
            topv[t] = m; topi[t] = midx;
            sv[mpos] = -1e30f;
        }
        __syncthreads();
    }
    if (lane == 0) {
        if (topv[KNN - 1] - topv[KNN] >= GAP_THRESH) {
#pragma unroll
            for (int t = 0; t < KNN; ++t) idx6[row * KNN + t] = topi[t];
        } else {
            int p = atomicAdd(cnt, 1);
            wl[p] = row;
        }
    }
}

// ---------------------------------------------------------------------------
// Exact (f64) rescore of ambiguous rows only (worklist-driven; early-exit
// past count). 256 threads, wave w handles candidates w, w+4, w+8.
__global__ void rescore_kernel(const float* __restrict__ x,
                               const double* __restrict__ invnorm,
                               const int* __restrict__ cand,
                               const int* __restrict__ wl,
                               const int* __restrict__ cnt,
                               int* __restrict__ idx6) {
    if (blockIdx.x >= *cnt) return;          // uniform per block
    int row = wl[blockIdx.x];
    int tid = threadIdx.x;                   // 256 threads
    int wave = tid >> 6, lane = tid & 63;
    __shared__ float4 xi4[DIM / 4];
    __shared__ double simv[NCAND];
    __shared__ int    cnd[NCAND];
    const float4* xr4 = (const float4*)(x + (size_t)row * DIM);
    xi4[tid] = xr4[tid]; xi4[tid + 256] = xr4[tid + 256];
    if (tid < NCAND) cnd[tid] = cand[row * NCAND + tid];
    __syncthreads();
    for (int t = wave; t < NCAND; t += 4) {
        int j = cnd[t];
        if (j == row) { if (lane == 0) simv[t] = 1e30; continue; }  // self: rank 1
        const float4* xj4 = (const float4*)(x + (size_t)j * DIM);
        double s = 0.0;
        for (int k = lane; k < DIM / 4; k += 64) {
            float4 a = xj4[k], bq = xi4[k];
            s += (double)a.x * bq.x + (double)a.y * bq.y +
                 (double)a.z * bq.z + (double)a.w * bq.w;
        }
#pragma unroll
        for (int off = 32; off; off >>= 1) s += __shfl_xor(s, off);
        if (lane == 0) simv[t] = s * invnorm[row] * invnorm[j];
    }
    __syncthreads();
    if (tid == 0) {
        double vals[NCAND]; int idxs[NCAND];
        for (int t = 0; t < NCAND; ++t) { vals[t] = simv[t]; idxs[t] = cnd[t]; }
        for (int t = 0; t < KNN; ++t) {
            int best = 0; double bvv = -1e300; int bji = 0x7fffffff;
            for (int e = 0; e < NCAND; ++e) {
                if (vals[e] > bvv || (vals[e] == bvv && idxs[e] < bji)) {
                    bvv = vals[e]; best = e; bji = idxs[e];
                }
            }
            idx6[row * KNN + t] = idxs[best];
            vals[best] = -1e300;
        }
    }
}

// ---------------------------------------------------------------------------
// GIN aggregation with reciprocal mask: h0 = 1.3*x_i + sum reciprocal x_j -> bf16
__global__ void aggregate_kernel(const float* __restrict__ x,
                                 const int* __restrict__ idx6,
                                 __hip_bfloat16* __restrict__ h0) {
    int row = blockIdx.x, tid = threadIdx.x;   // 256 threads
    __shared__ int nb[KNN];
    __shared__ int fl[KNN];
    if (tid < KNN) {
        int j = idx6[row * KNN + tid];
        nb[tid] = j;
        int f = 0;
        for (int t = 0; t < KNN; ++t) if (idx6[j * KNN + t] == row) f = 1;
        fl[tid] = f;
    }
    __syncthreads();
    int f0 = tid * 8;
    const float4* xr4 = (const float4*)(x + (size_t)row * DIM + f0);
    float4 a0 = xr4[0], a1 = xr4[1];
    float acc[8] = {1.3f * a0.x, 1.3f * a0.y, 1.3f * a0.z, 1.3f * a0.w,
                    1.3f * a1.x, 1.3f * a1.y, 1.3f * a1.z, 1.3f * a1.w};
    for (int t = 0; t < KNN; ++t) {
        if (fl[t]) {
            const float4* xj4 = (const float4*)(x + (size_t)nb[t] * DIM + f0);
            float4 b0 = xj4[0], b1 = xj4[1];
            acc[0] += b0.x; acc[1] += b0.y; acc[2] += b0.z; acc[3] += b0.w;
            acc[4] += b1.x; acc[5] += b1.y; acc[6] += b1.z; acc[7] += b1.w;
        }
    }
#pragma unroll
    for (int u = 0; u < 8; ++u)
        h0[(size_t)row * DIM + f0 + u] = __float2bfloat16(acc[u]);
}

// ---------------------------------------------------------------------------
__global__ void bn_finalize_kernel(float* __restrict__ stats,
                                   const float* __restrict__ gamma,
                                   const float* __restrict__ beta) {
    int c = blockIdx.x * 256 + threadIdx.x;         // 2048
    float mean = stats[c] * (1.0f / 8192.0f);
    float var  = stats[DIM + c] * (1.0f / 8192.0f) - mean * mean;
    float sc   = gamma[c] / sqrtf(var + 1e-5f);
    stats[2 * DIM + c] = sc;                        // scale
    stats[3 * DIM + c] = beta[c] - mean * sc;       // shift
}

// Fold BN into classifier: wcs[c,k] = wc[c,k]*scale[k] (bf16, zero-padded rows),
// lb[c] = sum_k shift[k]*wc[c,k].
__global__ void wc_fold_kernel(const float* __restrict__ wc,
                               const float* __restrict__ stats,
                               __hip_bfloat16* __restrict__ wcs,
                               float* __restrict__ lb) {
    int r = blockIdx.x, tid = threadIdx.x;          // 768 blocks x 256
    int k0 = tid * 8;
    float part = 0.f;
    if (r < NCLS) {
#pragma unroll
        for (int u = 0; u < 8; ++u) {
            int k = k0 + u;
            float w = wc[(size_t)r * DIM + k];
            wcs[(size_t)r * DIM + k] = __float2bfloat16(w * stats[2 * DIM + k]);
            part += w * stats[3 * DIM + k];
        }
    } else {
#pragma unroll
        for (int u = 0; u < 8; ++u)
            wcs[(size_t)r * DIM + k0 + u] = __float2bfloat16(0.f);
    }
    __shared__ float red[256];
    red[tid] = part; __syncthreads();
    for (int off = 128; off; off >>= 1) {
        if (tid < off) red[tid] += red[tid + off];
        __syncthreads();
    }
    if (tid == 0) lb[r] = red[0];
}

// ---------------------------------------------------------------------------
__global__ void f32_to_bf16_kernel(const float* __restrict__ src,
                                   __hip_bfloat16* __restrict__ dst, int n4) {
    int i = blockIdx.x * 256 + threadIdx.x;
    if (i < n4) {
        float4 v = ((const float4*)src)[i];
        __hip_bfloat16* o = dst + (size_t)i * 4;
        o[0] = __float2bfloat16(v.x); o[1] = __float2bfloat16(v.y);
        o[2] = __float2bfloat16(v.z); o[3] = __float2bfloat16(v.w);
    }
}

// ---------------------------------------------------------------------------
extern "C" void kernel_launch(void* const* d_in, const int* in_sizes, int n_in,
                              void* d_out, int out_size, void* d_ws, size_t ws_size,
                              hipStream_t stream) {
    const float* x     = (const float*)d_in[0];
    const float* w1    = (const float*)d_in[1];
    const float* b1    = (const float*)d_in[2];
    const float* w2    = (const float*)d_in[3];
    const float* b2    = (const float*)d_in[4];
    const float* gamma = (const float*)d_in[5];
    const float* beta  = (const float*)d_in[6];
    const float* wc    = (const float*)d_in[7];
    float* out = (float*)d_out;

    char* ws = (char*)d_ws;
    size_t off = 0;
    auto alloc = [&](size_t bytes) -> void* {
        void* p = ws + off;
        off += (bytes + 255) & ~(size_t)255;
        return p;
    };

    __hip_bfloat16* xnb  = (__hip_bfloat16*)alloc((size_t)N_ROWS * DIM * 2);    // 32 MB (reused: h0)
    __hip_bfloat16* S    = (__hip_bfloat16*)alloc((size_t)N_ROWS * N_ROWS * 2); // 128 MB (reused: z1, z2b)
    double*         invn = (double*)alloc((size_t)N_ROWS * 8);
    int*            cand = (int*)alloc((size_t)N_ROWS * NCAND * 4);
    int*            idx6 = (int*)alloc((size_t)N_ROWS * KNN * 4);
    __hip_bfloat16* w1b  = (__hip_bfloat16*)alloc((size_t)DIM * DIM * 2);
    __hip_bfloat16* w2b  = (__hip_bfloat16*)alloc((size_t)DIM * DIM * 2);
    __hip_bfloat16* wcs  = (__hip_bfloat16*)alloc((size_t)NPAD * DIM * 2);
    float*          lb   = (float*)alloc((size_t)NPAD * 4);
    float*          stats = (float*)alloc((size_t)4 * DIM * 4);
    int*            wl   = (int*)alloc((size_t)N_ROWS * 4);
    int*            cnt  = (int*)alloc((size_t)256);

    __hip_bfloat16* h0  = xnb;                          // xn dead after syrk
    __hip_bfloat16* z1  = S;                            // S dead after topk
    __hip_bfloat16* z2b = S + (size_t)N_ROWS * DIM;     // next 32 MB of S region

    hipMemsetAsync(stats, 0, 2 * DIM * sizeof(float), stream);
    hipMemsetAsync(cnt, 0, sizeof(int), stream);

    normalize_kernel<<<N_ROWS, 256, 0, stream>>>(x, xnb, invn);
    f32_to_bf16_kernel<<<(DIM * DIM / 4) / 256, 256, 0, stream>>>(w1, w1b, DIM * DIM / 4);
    f32_to_bf16_kernel<<<(DIM * DIM / 4) / 256, 256, 0, stream>>>(w2, w2b, DIM * DIM / 4);

    // S = xn xn^T, upper-triangle 256x256 tiles only (+transposed writes)
    gemm_syrk<<<528, 512, 0, stream>>>(xnb, S);

    topk_cand_kernel<<<N_ROWS, 64, 0, stream>>>(S, cand, idx6, wl, cnt);
    rescore_kernel<<<N_ROWS, 256, 0, stream>>>(x, invn, cand, wl, cnt, idx6);
    aggregate_kernel<<<N_ROWS, 256, 0, stream>>>(x, idx6, h0);

    // z1 = relu(h0 @ w1^T + b1)   [bf16]
    gemm_nt<1, 128><<<dim3(DIM / 128, N_ROWS / 128), 256, 0, stream>>>(
        h0, w1b, (void*)z1, b1, nullptr, DIM, DIM, 0);
    // z2b = h@w2^T + b2 [bf16] with fused BN column stats
    gemm_nt<4, 128><<<dim3(DIM / 128, N_ROWS / 128), 256, 0, stream>>>(
        z1, w2b, (void*)z2b, b2, stats, DIM, DIM, 0);

    bn_finalize_kernel<<<DIM / 256, 256, 0, stream>>>(stats, gamma, beta);
    wc_fold_kernel<<<NPAD, 256, 0, stream>>>(wc, stats, wcs, lb);

    // logits = (z2*scale+shift) @ wc^T = z2b @ wcs^T + lb   [fp32, col<751]
    gemm_nt<5, 64><<<dim3(NPAD / 128, N_ROWS / 64), 256, 0, stream>>>(
        z2b, wcs, (void*)out, lb, nullptr, DIM, NCLS, NCLS);
}

// Round 2
// 712.630 us; speedup vs baseline: 1.0768x; 1.0768x over previous
//
#include <hip/hip_runtime.h>
#include <hip/hip_bf16.h>

// Problem constants
#define N_ROWS 8192
#define DIM    2048
#define NCLS   751
#define NPAD   768     // wc padded rows (6*128)
#define KNN    6       // K+1 neighbors (incl self)
#define NCAND  12      // rescore candidates (gap(6,12) >> bf16 quant error)
#define GAP_THRESH 1.25e-3f   // bf16 rank-6/7 gap above which top-6 set is exact

typedef __attribute__((ext_vector_type(8))) short bf16x8;
typedef __attribute__((ext_vector_type(4))) float f32x4;

// ---------------------------------------------------------------------------
// async global->LDS, 16B per lane. LDS dest must be wave-uniform base + lane*16.
__device__ __forceinline__ void async_ld16(const __hip_bfloat16* g, __hip_bfloat16* l) {
    __builtin_amdgcn_global_load_lds(
        (__attribute__((address_space(1))) void*)(g),
        (__attribute__((address_space(3))) void*)(l), 16, 0, 0);
}

__device__ __forceinline__ float bf16_to_f32(short s) {
    union { float f; unsigned u; } cv;
    cv.u = ((unsigned)(unsigned short)s) << 16;
    return cv.f;
}

// ---------------------------------------------------------------------------
// Row L2 norms (f64-accurate) + bf16 normalized rows for the similarity GEMM.
__global__ void normalize_kernel(const float* __restrict__ x,
                                 __hip_bfloat16* __restrict__ xnb,
                                 double* __restrict__ invnorm) {
    int row = blockIdx.x, tid = threadIdx.x;   // 256 threads
    const float4* xr4 = (const float4*)(x + (size_t)row * DIM);
    float4 v0 = xr4[tid], v1 = xr4[tid + 256];
    double s = (double)v0.x * v0.x + (double)v0.y * v0.y +
               (double)v0.z * v0.z + (double)v0.w * v0.w +
               (double)v1.x * v1.x + (double)v1.y * v1.y +
               (double)v1.z * v1.z + (double)v1.w * v1.w;
    __shared__ double red[256];
    red[tid] = s; __syncthreads();
    for (int off = 128; off; off >>= 1) {
        if (tid < off) red[tid] += red[tid + off];
        __syncthreads();
    }
    double norm = sqrt(red[0]);
    if (norm < 1e-12) norm = 1e-12;
    double inv = 1.0 / norm;
    if (tid == 0) invnorm[row] = inv;
    float invf = (float)inv;
    __hip_bfloat16* o0 = xnb + (size_t)row * DIM + tid * 4;
    o0[0] = __float2bfloat16(v0.x * invf);
    o0[1] = __float2bfloat16(v0.y * invf);
    o0[2] = __float2bfloat16(v0.z * invf);
    o0[3] = __float2bfloat16(v0.w * invf);
    __hip_bfloat16* o1 = o0 + 1024;
    o1[0] = __float2bfloat16(v1.x * invf);
    o1[1] = __float2bfloat16(v1.y * invf);
    o1[2] = __float2bfloat16(v1.z * invf);
    o1[3] = __float2bfloat16(v1.w * invf);
}

// ===========================================================================
// R2 tile engine: BM x 256 output tile, K = DIM = 2048, BK = 64, 8 waves
// (512 thr, 2M x 4N; per-wave BM/2 x 64), full-tile double-buffered LDS,
// 4 phases per K-step (m201-style):
//   p0: ds_read A(mh0,12-BM/64*? see below)+B(nh0); stage B{j0,j1};  16 MFMA (mh0,nh0)
//   p1: ds_read B(nh1);             stage B{j2,j3}; vmcnt(4); 16 MFMA (mh0,nh1)
//   p2: ds_read A(mh1);             stage A{j0,j2};            16 MFMA (mh1,nh1)
//   p3: (frags in regs);            stage A{j1,j3}; vmcnt(2);  16 MFMA (mh1,nh0)
// each phase: reads+stage -> s_barrier -> lgkmcnt(0) -> sched_barrier(0) ->
// setprio(1) -> MFMA -> setprio(0) [-> counted vmcnt] -> s_barrier.
//
// Counted-wait ledger (FIFO outstanding per wave, BM=256, steady state):
//  - at p1 tail: {prev-p3 A pair, p0 B pair, p1 B pair} = 6 -> vmcnt(4)
//    drains prev-p3's A{j1,j3} (needed by p2's reads of rows 64-127/192-255).
//  - at p3 tail: {p0 B, p1 B, p2 A, p3 A} = 8 -> vmcnt(2) drains B (all 4
//    passes partially read at next-p0) + A{j0,j2} (rows 0-63/128-191, read
//    at next-p0); A{j1,j3} stays in flight (>= 2.5 phases slack to its use).
//  - buffer overwrite: stage into buf^1 starts after the close barrier of
//    the iteration that last read buf^1 -> race-free.
// Accumulation order per acc element: kt ascending, kslice s ascending ->
// bit-identical to the R0/R1 kernels' results.
// EPI: 0 = syrk store (bf16 direct + LDS-transposed write, always both)
//      1 = relu(v+bias) -> bf16     4 = v+bias -> bf16 + BN column stats
// ===========================================================================
template <int BM, int EPI>
__device__ __forceinline__ void tile_engine(
    const __hip_bfloat16* __restrict__ Aptr,
    const __hip_bfloat16* __restrict__ Bptr,
    char* __restrict__ smem,
    size_t bm, size_t bn,
    __hip_bfloat16* __restrict__ S,
    void* __restrict__ Cv,
    const float* __restrict__ bias,
    float* __restrict__ stats)
{
    constexpr int MI = BM / 32;                     // 8 or 4
    constexpr size_t ABYTES = (size_t)BM * 128;     // A tile bytes (BM x 64 bf16)
    constexpr size_t BUFS = ABYTES + 32768;         // + B tile (256 x 64 bf16)
    const int tid  = threadIdx.x;                   // 512 threads
    const int wave = tid >> 6, lane = tid & 63;
    const int wm = (wave >> 2) * (BM / 2), wn = (wave & 3) * 64;
    const int quad = lane >> 4, l15 = lane & 15;

    // staging: thread's fixed row/chunk within a 64-row pass
    const int srow = tid >> 3;                      // 0..63
    const int gsw  = ((tid & 7) ^ (srow & 7)) * 8;  // swizzled k-chunk (inverse of read)
    const __hip_bfloat16* gA = Aptr + (bm + srow) * (size_t)DIM + gsw;
    const __hip_bfloat16* gB = Bptr + (bn + srow) * (size_t)DIM + gsw;

    auto Asbuf = [&](int c) { return (__hip_bfloat16*)(smem + c * BUFS); };
    auto Bsbuf = [&](int c) { return (__hip_bfloat16*)(smem + c * BUFS + ABYTES); };

    f32x4 acc[MI][4];
#pragma unroll
    for (int mi = 0; mi < MI; ++mi)
#pragma unroll
        for (int ni = 0; ni < 4; ++ni)
            acc[mi][ni] = (f32x4){0.f, 0.f, 0.f, 0.f};

    constexpr int KT = DIM / 64;                    // 32 K-steps

    // ---- prologue: stage tile 0 into buf 0 (order so last pair = A{j1,j3})
    {
        __hip_bfloat16* Ad = Asbuf(0);
        __hip_bfloat16* Bd = Bsbuf(0);
        async_ld16(gB,             Bd + tid * 8);
        async_ld16(gB +  64 * DIM, Bd + tid * 8 + 4096);
        async_ld16(gB + 128 * DIM, Bd + tid * 8 + 8192);
        async_ld16(gB + 192 * DIM, Bd + tid * 8 + 12288);
        if constexpr (BM == 256) {
            async_ld16(gA,             Ad + tid * 8);
            async_ld16(gA + 128 * DIM, Ad + tid * 8 + 8192);
            async_ld16(gA +  64 * DIM, Ad + tid * 8 + 4096);
            async_ld16(gA + 192 * DIM, Ad + tid * 8 + 12288);
            asm volatile("s_waitcnt vmcnt(2)" ::: "memory");
        } else {
            async_ld16(gA,            Ad + tid * 8);
            async_ld16(gA + 64 * DIM, Ad + tid * 8 + 4096);
            asm volatile("s_waitcnt vmcnt(0)" ::: "memory");
        }
        __builtin_amdgcn_s_barrier();
    }

#pragma unroll 1
    for (int kt = 0; kt < KT; ++kt) {
        const int cur = kt & 1;
        __hip_bfloat16* As = Asbuf(cur);
        __hip_bfloat16* Bs = Bsbuf(cur);
        __hip_bfloat16* An = Asbuf(cur ^ 1);
        __hip_bfloat16* Bn = Bsbuf(cur ^ 1);
        const bool st = (kt < KT - 1);
        const size_t kbn = (size_t)(kt + 1) * 64;

        bf16x8 af[2][MI / 2], b0[2][2], b1[2][2];

        // ---------------- P0: reads A(mh0)+B(nh0); stage B{j0,j1}
#pragma unroll
        for (int s = 0; s < 2; ++s) {
#pragma unroll
            for (int m = 0; m < MI / 2; ++m) {
                int rr = wm + m * 16 + l15;
                af[s][m] = *(const bf16x8*)&As[(rr * 8 + ((s * 4 + quad) ^ (rr & 7))) * 8];
            }
#pragma unroll
            for (int n = 0; n < 2; ++n) {
                int rr = wn + n * 16 + l15;
                b0[s][n] = *(const bf16x8*)&Bs[(rr * 8 + ((s * 4 + quad) ^ (rr & 7))) * 8];
            }
        }
        if (st) {
            async_ld16(gB + kbn,            Bn + tid * 8);
            async_ld16(gB + kbn + 64 * DIM, Bn + tid * 8 + 4096);
        }
        __builtin_amdgcn_s_barrier();
        asm volatile("s_waitcnt lgkmcnt(0)" ::: "memory");
        __builtin_amdgcn_sched_barrier(0);
        __builtin_amdgcn_s_setprio(1);
#pragma unroll
        for (int s = 0; s < 2; ++s)
#pragma unroll
            for (int m = 0; m < MI / 2; ++m)
#pragma unroll
                for (int n = 0; n < 2; ++n)
                    acc[m][n] = __builtin_amdgcn_mfma_f32_16x16x32_bf16(
                        af[s][m], b0[s][n], acc[m][n], 0, 0, 0);
        __builtin_amdgcn_s_setprio(0);
        __builtin_amdgcn_s_barrier();

        // ---------------- P1: reads B(nh1); stage B{j2,j3}; mid vmcnt
#pragma unroll
        for (int s = 0; s < 2; ++s)
#pragma unroll
            for (int n = 0; n < 2; ++n) {
                int rr = wn + 32 + n * 16 + l15;
                b1[s][n] = *(const bf16x8*)&Bs[(rr * 8 + ((s * 4 + quad) ^ (rr & 7))) * 8];
            }
        if (st) {
            async_ld16(gB + kbn + 128 * DIM, Bn + tid * 8 + 8192);
            async_ld16(gB + kbn + 192 * DIM, Bn + tid * 8 + 12288);
        }
        __builtin_amdgcn_s_barrier();
        asm volatile("s_waitcnt lgkmcnt(0)" ::: "memory");
        __builtin_amdgcn_sched_barrier(0);
        __builtin_amdgcn_s_setprio(1);
#pragma unroll
        for (int s = 0; s < 2; ++s)
#pragma unroll
            for (int m = 0; m < MI / 2; ++m)
#pragma unroll
                for (int n = 0; n < 2; ++n)
                    acc[m][2 + n] = __builtin_amdgcn_mfma_f32_16x16x32_bf16(
                        af[s][m], b1[s][n], acc[m][2 + n], 0, 0, 0);
        __builtin_amdgcn_s_setprio(0);
        if (st) { asm volatile("s_waitcnt vmcnt(4)" ::: "memory"); }
        else    { asm volatile("s_waitcnt vmcnt(0)" ::: "memory"); }
        __builtin_amdgcn_s_barrier();

        // ---------------- P2: reads A(mh1); stage A pair 1
#pragma unroll
        for (int s = 0; s < 2; ++s)
#pragma unroll
            for (int m = 0; m < MI / 2; ++m) {
                int rr = wm + (BM / 4) + m * 16 + l15;
                af[s][m] = *(const bf16x8*)&As[(rr * 8 + ((s * 4 + quad) ^ (rr & 7))) * 8];
            }
        if (st) {
            if constexpr (BM == 256) {
                async_ld16(gA + kbn,             An + tid * 8);
                async_ld16(gA + kbn + 128 * DIM, An + tid * 8 + 8192);
            } else {
                async_ld16(gA + kbn,            An + tid * 8);
                async_ld16(gA + kbn + 64 * DIM, An + tid * 8 + 4096);
            }
        }
        __builtin_amdgcn_s_barrier();
        asm volatile("s_waitcnt lgkmcnt(0)" ::: "memory");
        __builtin_amdgcn_sched_barrier(0);
        __builtin_amdgcn_s_setprio(1);
#pragma unroll
        for (int s = 0; s < 2; ++s)
#pragma unroll
            for (int m = 0; m < MI / 2; ++m)
#pragma unroll
                for (int n = 0; n < 2; ++n)
                    acc[MI / 2 + m][2 + n] = __builtin_amdgcn_mfma_f32_16x16x32_bf16(
                        af[s][m], b1[s][n], acc[MI / 2 + m][2 + n], 0, 0, 0);
        __builtin_amdgcn_s_setprio(0);
        __builtin_amdgcn_s_barrier();

        // ---------------- P3: no reads; stage A pair 2 (BM=256); close vmcnt
        if (st) {
            if constexpr (BM == 256) {
                async_ld16(gA + kbn +  64 * DIM, An + tid * 8 + 4096);
                async_ld16(gA + kbn + 192 * DIM, An + tid * 8 + 12288);
            }
        }
        __builtin_amdgcn_s_setprio(1);
#pragma unroll
        for (int s = 0; s < 2; ++s)
#pragma unroll
            for (int m = 0; m < MI / 2; ++m)
#pragma unroll
                for (int n = 0; n < 2; ++n)
                    acc[MI / 2 + m][n] = __builtin_amdgcn_mfma_f32_16x16x32_bf16(
                        af[s][m], b0[s][n], acc[MI / 2 + m][n], 0, 0, 0);
        __builtin_amdgcn_s_setprio(0);
        if (st && BM == 256) { asm volatile("s_waitcnt vmcnt(2)" ::: "memory"); }
        else                 { asm volatile("s_waitcnt vmcnt(0)" ::: "memory"); }
        __builtin_amdgcn_s_barrier();
    }

    // ---------------- epilogues
    if constexpr (EPI == 0) {
        // direct store (C/D layout: col=lane&15, row=quad*4+e)
#pragma unroll
        for (int mi = 0; mi < MI; ++mi)
#pragma unroll
            for (int ni = 0; ni < 4; ++ni)
#pragma unroll
                for (int e = 0; e < 4; ++e) {
                    size_t row = bm + wm + mi * 16 + quad * 4 + e;
                    size_t col = bn + wn + ni * 16 + l15;
                    S[row * N_ROWS + col] = __float2bfloat16(acc[mi][ni][e]);
                }
        // transposed tile via LDS (8 passes of 32 cols), vector stores
        __hip_bfloat16* T = (__hip_bfloat16*)smem;
        constexpr int TSTR = BM + 8;
#pragma unroll
        for (int p = 0; p < 8; ++p) {
            __syncthreads();
            if ((wave & 3) == (p >> 1)) {
#pragma unroll
                for (int nio = 0; nio < 2; ++nio) {
                    const int ni = (p & 1) * 2 + nio;
                    const int tc = ni * 16 + l15 - (p & 1) * 32;   // 0..31
#pragma unroll
                    for (int mi = 0; mi < MI; ++mi)
#pragma unroll
                        for (int e = 0; e < 4; ++e) {
                            int r = wm + mi * 16 + quad * 4 + e;
                            T[tc * TSTR + r] = __float2bfloat16(acc[mi][ni][e]);
                        }
                }
            }
            __syncthreads();
#pragma unroll
            for (int j2 = 0; j2 < BM / 128; ++j2) {
                int q = tid + 512 * j2;
                int tc = q / (BM / 8), r8 = (q % (BM / 8)) * 8;
                *(bf16x8*)&S[(bn + p * 32 + tc) * (size_t)N_ROWS + bm + r8] =
                    *(const bf16x8*)&T[tc * TSTR + r8];
            }
        }
    } else {
        float s1[4] = {0.f, 0.f, 0.f, 0.f}, s2[4] = {0.f, 0.f, 0.f, 0.f};
#pragma unroll
        for (int mi = 0; mi < MI; ++mi)
#pragma unroll
            for (int ni = 0; ni < 4; ++ni)
#pragma unroll
                for (int e = 0; e < 4; ++e) {
                    size_t row = bm + wm + mi * 16 + quad * 4 + e;
                    int col = (int)(bn + wn + ni * 16 + l15);
                    float v = acc[mi][ni][e] + bias[col];
                    if constexpr (EPI == 1) v = v > 0.f ? v : 0.f;
                    ((__hip_bfloat16*)Cv)[row * (size_t)DIM + col] = __float2bfloat16(v);
                    if constexpr (EPI == 4) { s1[ni] += v; s2[ni] += v * v; }
                }
        if constexpr (EPI == 4) {
            __syncthreads();
            float* sred = (float*)smem;     // [2 M-halves][256 cols][2 stats]
#pragma unroll
            for (int ni = 0; ni < 4; ++ni) {
                float a = s1[ni], bq = s2[ni];
                a += __shfl_xor(a, 16);  a += __shfl_xor(a, 32);
                bq += __shfl_xor(bq, 16); bq += __shfl_xor(bq, 32);
                if (lane < 16) {
                    int c = wn + ni * 16 + l15;
                    sred[((wave >> 2) * 256 + c) * 2 + 0] = a;
                    sred[((wave >> 2) * 256 + c) * 2 + 1] = bq;
                }
            }
            __syncthreads();
            if (tid < 256) {
                float ta = sred[tid * 2] + sred[(256 + tid) * 2];
                float tb = sred[tid * 2 + 1] + sred[(256 + tid) * 2 + 1];
                atomicAdd(&stats[bn + tid], ta);
                atomicAdd(&stats[DIM + bn + tid], tb);
            }
        }
    }
}

// ---------------------------------------------------------------------------
// Triangular symmetric GEMM via tile_engine. Grid = 560 blocks:
//   b in [0,64):  diagonal half-blocks 128x256 (dispatched FIRST so the short
//                 blocks retire early and CUs backfill -> ~2.1 round wall)
//   b in [64,560): strict upper-triangle 256x256 tiles (496)
// Every block writes its tile directly AND transposed; overlapping writes in
// the diagonal band carry identical bf16 values (symmetry) -> idempotent.
__global__ __launch_bounds__(512, 2)
void gemm_syrk(const __hip_bfloat16* __restrict__ A,
               __hip_bfloat16* __restrict__ S) {
    __shared__ __align__(16) char smem[2 * (256 * 128 + 32768)];   // 128 KB
    int b = blockIdx.x;
    if (b < 64) {
        int ti = b >> 1, half = b & 1;
        tile_engine<128, 0>(A, A, smem,
                            (size_t)ti * 256 + (size_t)half * 128,
                            (size_t)ti * 256, S, nullptr, nullptr, nullptr);
    } else {
        int bb = b - 64;      // strict upper pair (bi < bj), 32 panels
        int bi = (int)((63.0 - sqrt(3969.0 - 8.0 * (double)bb)) * 0.5);
        while (31 * (bi + 1) - (bi + 1) * bi / 2 <= bb) ++bi;
        while (bi > 0 && 31 * bi - bi * (bi - 1) / 2 > bb) --bi;
        int bj = bi + 1 + (bb - (31 * bi - bi * (bi - 1) / 2));
        tile_engine<256, 0>(A, A, smem, (size_t)bi * 256, (size_t)bj * 256,
                            S, nullptr, nullptr, nullptr);
    }
}

// ---------------------------------------------------------------------------
// 256x256 NT GEMM via tile_engine (grid (DIM/256, N_ROWS/256) = 256 blocks =
// exactly 1 block/CU, no tail). EPI 1/4 as before.
template <int EPI>
__global__ __launch_bounds__(512, 2)
void gemm_nt_256(const __hip_bfloat16* __restrict__ A,
                 const __hip_bfloat16* __restrict__ B,
                 void* __restrict__ Cv,
                 const float* __restrict__ bias,
                 float* __restrict__ stats) {
    __shared__ __align__(16) char smem[2 * (256 * 128 + 32768)];   // 128 KB
    tile_engine<256, EPI>(A, B, smem,
                          (size_t)blockIdx.y * 256, (size_t)blockIdx.x * 256,
                          nullptr, Cv, bias, stats);
}

// ---------------------------------------------------------------------------
// Generic NT bf16 GEMM, BK=64 (kept for the classifier: EPI 5, TM=64).
template <int EPI, int TM>
__global__ __launch_bounds__(256)
void gemm_nt(const __hip_bfloat16* __restrict__ A,
             const __hip_bfloat16* __restrict__ B,
             void* __restrict__ Cv,
             const float* __restrict__ bias,
             float* __restrict__ stats,
             int K, int ldc, int ncols) {
    constexpr int MI = TM / 32;                       // 4 or 2
    __shared__ __align__(16) char smem[TM * 128 + 16384];
    __hip_bfloat16* As = (__hip_bfloat16*)smem;                // TM x 64
    __hip_bfloat16* Bs = (__hip_bfloat16*)(smem + TM * 128);   // 128 x 64
    const int tid  = threadIdx.x;
    const size_t bm = (size_t)blockIdx.y * TM, bn = (size_t)blockIdx.x * 128;
    const int wave = tid >> 6, lane = tid & 63;
    const int wm = (wave & 1) * (TM / 2), wn = (wave >> 1) * 64;
    const int quad = lane >> 4, l15 = lane & 15;

    f32x4 acc[MI][4];
#pragma unroll
    for (int mi = 0; mi < MI; ++mi)
#pragma unroll
        for (int ni = 0; ni < 4; ++ni)
            acc[mi][ni] = (f32x4){0.f, 0.f, 0.f, 0.f};

    const int KT = K >> 6;
    for (int kt = 0; kt < KT; ++kt) {
        const int kb = kt << 6;
        __syncthreads();
#pragma unroll
        for (int j = 0; j < TM / 32; ++j) {
            int q = tid + 256 * j, r = q >> 3, g = ((q & 7) ^ (r & 7)) * 8;
            async_ld16(A + (bm + r) * (size_t)K + kb + g, As + q * 8);
        }
#pragma unroll
        for (int j = 0; j < 4; ++j) {
            int q = tid + 256 * j, r = q >> 3, g = ((q & 7) ^ (r & 7)) * 8;
            async_ld16(B + (bn + r) * (size_t)K + kb + g, Bs + q * 8);
        }
        __syncthreads();

#pragma unroll
        for (int s = 0; s < 2; ++s) {
            bf16x8 af[MI], bfr[4];
#pragma unroll
            for (int mi = 0; mi < MI; ++mi) {
                int rr = wm + mi * 16 + l15;
                af[mi] = *(const bf16x8*)&As[(rr * 8 + ((s * 4 + quad) ^ (rr & 7))) * 8];
            }
#pragma unroll
            for (int ni = 0; ni < 4; ++ni) {
                int rr = wn + ni * 16 + l15;
                bfr[ni] = *(const bf16x8*)&Bs[(rr * 8 + ((s * 4 + quad) ^ (rr & 7))) * 8];
            }
#pragma unroll
            for (int mi = 0; mi < MI; ++mi)
#pragma unroll
                for (int ni = 0; ni < 4; ++ni)
                    acc[mi][ni] = __builtin_amdgcn_mfma_f32_16x16x32_bf16(
                        af[mi], bfr[ni], acc[mi][ni], 0, 0, 0);
        }
    }

#pragma unroll
    for (int mi = 0; mi < MI; ++mi)
#pragma unroll
        for (int ni = 0; ni < 4; ++ni)
#pragma unroll
            for (int e = 0; e < 4; ++e) {
                size_t row = bm + wm + mi * 16 + quad * 4 + e;
                int col = (int)(bn + wn + ni * 16 + l15);
                float v = acc[mi][ni][e];
                v += bias[col];
                if (col < ncols)
                    ((float*)Cv)[row * (size_t)ldc + col] = v;
            }
}

// ---------------------------------------------------------------------------
// Per-row top-NCAND candidates from bf16 similarity row. 1 wave per row.
__global__ void topk_cand_kernel(const __hip_bfloat16* __restrict__ S,
                                 int* __restrict__ cand,
                                 int* __restrict__ idx6,
                                 int* __restrict__ wl,
                                 int* __restrict__ cnt) {
    int row = blockIdx.x, lane = threadIdx.x;   // 64 threads
    const bf16x8* Sr8 = (const bf16x8*)(S + (size_t)row * N_ROWS);
    float bv[6]; int bi6[6];
#pragma unroll
    for (int t = 0; t < 6; ++t) { bv[t] = -1e30f; bi6[t] = -1; }
    float vmin = -1e30f;
    for (int it = 0; it < N_ROWS / (64 * 8); ++it) {
        int c8 = it * 64 + lane;
        bf16x8 v8 = Sr8[c8];
#pragma unroll
        for (int u = 0; u < 8; ++u) {
            float v = bf16_to_f32(v8[u]);
            if (v > vmin) {
                int ms = 0; float mv = bv[0];
#pragma unroll
                for (int t = 1; t < 6; ++t) if (bv[t] < mv) { mv = bv[t]; ms = t; }
                bv[ms] = v; bi6[ms] = c8 * 8 + u;
                vmin = bv[0];
#pragma unroll
                for (int t = 1; t < 6; ++t) vmin = fminf(vmin, bv[t]);
            }
        }
    }
    __shared__ float sv[384];
    __shared__ int   si[384];
    __shared__ float topv[NCAND];
    __shared__ int   topi[NCAND];
#pragma unroll
    for (int t = 0; t < 6; ++t) { sv[lane * 6 + t] = bv[t]; si[lane * 6 + t] = bi6[t]; }
    __syncthreads();
    for (int t = 0; t < NCAND; ++t) {
        float m = -1e30f; int mpos = -1, midx = 0x7fffffff;
        for (int e = lane; e < 384; e += 64) {
            float v = sv[e]; int ix = si[e];
            if (v > m || (v == m && ix < midx)) { m = v; mpos = e; midx = ix; }
        }
#pragma unroll
        for (int off = 32; off; off >>= 1) {
            float ov = __shfl_xor(m, off);
            int   op = __shfl_xor(mpos, off);
            int   oi = __shfl_xor(midx, off);
            if (ov > m || (ov == m && oi < midx)) { m = ov; mpos = op; midx = oi; }
        }
        if (lane == 0) {
            cand[row * NCAND + t] = midx;
            topv[t] = m; topi[t] = midx;
            sv[mpos] = -1e30f;
        }
        __syncthreads();
    }
    if (lane == 0) {
        if (topv[KNN - 1] - topv[KNN] >= GAP_THRESH) {
#pragma unroll
            for (int t = 0; t < KNN; ++t) idx6[row * KNN + t] = topi[t];
        } else {
            int p = atomicAdd(cnt, 1);
            wl[p] = row;
        }
    }
}

// ---------------------------------------------------------------------------
// Exact (f64) rescore of ambiguous rows only (worklist-driven).
__global__ void rescore_kernel(const float* __restrict__ x,
                               const double* __restrict__ invnorm,
                               const int* __restrict__ cand,
                               const int* __restrict__ wl,
                               const int* __restrict__ cnt,
                               int* __restrict__ idx6) {
    if (blockIdx.x >= *cnt) return;          // uniform per block
    int row = wl[blockIdx.x];
    int tid = threadIdx.x;                   // 256 threads
    int wave = tid >> 6, lane = tid & 63;
    __shared__ float4 xi4[DIM / 4];
    __shared__ double simv[NCAND];
    __shared__ int    cnd[NCAND];
    const float4* xr4 = (const float4*)(x + (size_t)row * DIM);
    xi4[tid] = xr4[tid]; xi4[tid + 256] = xr4[tid + 256];
    if (tid < NCAND) cnd[tid] = cand[row * NCAND + tid];
    __syncthreads();
    for (int t = wave; t < NCAND; t += 4) {
        int j = cnd[t];
        if (j == row) { if (lane == 0) simv[t] = 1e30; continue; }  // self: rank 1
        const float4* xj4 = (const float4*)(x + (size_t)j * DIM);
        double s = 0.0;
        for (int k = lane; k < DIM / 4; k += 64) {
            float4 a = xj4[k], bq = xi4[k];
            s += (double)a.x * bq.x + (double)a.y * bq.y +
                 (double)a.z * bq.z + (double)a.w * bq.w;
        }
#pragma unroll
        for (int off = 32; off; off >>= 1) s += __shfl_xor(s, off);
        if (lane == 0) simv[t] = s * invnorm[row] * invnorm[j];
    }
    __syncthreads();
    if (tid == 0) {
        double vals[NCAND]; int idxs[NCAND];
        for (int t = 0; t < NCAND; ++t) { vals[t] = simv[t]; idxs[t] = cnd[t]; }
        for (int t = 0; t < KNN; ++t) {
            int best = 0; double bvv = -1e300; int bji = 0x7fffffff;
            for (int e = 0; e < NCAND; ++e) {
                if (vals[e] > bvv || (vals[e] == bvv && idxs[e] < bji)) {
                    bvv = vals[e]; best = e; bji = idxs[e];
                }
            }
            idx6[row * KNN + t] = idxs[best];
            vals[best] = -1e300;
        }
    }
}

// ---------------------------------------------------------------------------
// GIN aggregation with reciprocal mask: h0 = 1.3*x_i + sum reciprocal x_j -> bf16
__global__ void aggregate_kernel(const float* __restrict__ x,
                                 const int* __restrict__ idx6,
                                 __hip_bfloat16* __restrict__ h0) {
    int row = blockIdx.x, tid = threadIdx.x;   // 256 threads
    __shared__ int nb[KNN];
    __shared__ int fl[KNN];
    if (tid < KNN) {
        int j = idx6[row * KNN + tid];
        nb[tid] = j;
        int f = 0;
        for (int t = 0; t < KNN; ++t) if (idx6[j * KNN + t] == row) f = 1;
        fl[tid] = f;
    }
    __syncthreads();
    int f0 = tid * 8;
    const float4* xr4 = (const float4*)(x + (size_t)row * DIM + f0);
    float4 a0 = xr4[0], a1 = xr4[1];
    float acc[8] = {1.3f * a0.x, 1.3f * a0.y, 1.3f * a0.z, 1.3f * a0.w,
                    1.3f * a1.x, 1.3f * a1.y, 1.3f * a1.z, 1.3f * a1.w};
    for (int t = 0; t < KNN; ++t) {
        if (fl[t]) {
            const float4* xj4 = (const float4*)(x + (size_t)nb[t] * DIM + f0);
            float4 b0 = xj4[0], b1 = xj4[1];
            acc[0] += b0.x; acc[1] += b0.y; acc[2] += b0.z; acc[3] += b0.w;
            acc[4] += b1.x; acc[5] += b1.y; acc[6] += b1.z; acc[7] += b1.w;
        }
    }
#pragma unroll
    for (int u = 0; u < 8; ++u)
        h0[(size_t)row * DIM + f0 + u] = __float2bfloat16(acc[u]);
}

// ---------------------------------------------------------------------------
__global__ void bn_finalize_kernel(float* __restrict__ stats,
                                   const float* __restrict__ gamma,
                                   const float* __restrict__ beta) {
    int c = blockIdx.x * 256 + threadIdx.x;         // 2048
    float mean = stats[c] * (1.0f / 8192.0f);
    float var  = stats[DIM + c] * (1.0f / 8192.0f) - mean * mean;
    float sc   = gamma[c] / sqrtf(var + 1e-5f);
    stats[2 * DIM + c] = sc;                        // scale
    stats[3 * DIM + c] = beta[c] - mean * sc;       // shift
}

// Fold BN into classifier: wcs[c,k] = wc[c,k]*scale[k] (bf16, zero-padded rows),
// lb[c] = sum_k shift[k]*wc[c,k].
__global__ void wc_fold_kernel(const float* __restrict__ wc,
                               const float* __restrict__ stats,
                               __hip_bfloat16* __restrict__ wcs,
                               float* __restrict__ lb) {
    int r = blockIdx.x, tid = threadIdx.x;          // 768 blocks x 256
    int k0 = tid * 8;
    float part = 0.f;
    if (r < NCLS) {
#pragma unroll
        for (int u = 0; u < 8; ++u) {
            int k = k0 + u;
            float w = wc[(size_t)r * DIM + k];
            wcs[(size_t)r * DIM + k] = __float2bfloat16(w * stats[2 * DIM + k]);
            part += w * stats[3 * DIM + k];
        }
    } else {
#pragma unroll
        for (int u = 0; u < 8; ++u)
            wcs[(size_t)r * DIM + k0 + u] = __float2bfloat16(0.f);
    }
    __shared__ float red[256];
    red[tid] = part; __syncthreads();
    for (int off = 128; off; off >>= 1) {
        if (tid < off) red[tid] += red[tid + off];
        __syncthreads();
    }
    if (tid == 0) lb[r] = red[0];
}

// ---------------------------------------------------------------------------
__global__ void f32_to_bf16_kernel(const float* __restrict__ src,
                                   __hip_bfloat16* __restrict__ dst, int n4) {
    int i = blockIdx.x * 256 + threadIdx.x;
    if (i < n4) {
        float4 v = ((const float4*)src)[i];
        __hip_bfloat16* o = dst + (size_t)i * 4;
        o[0] = __float2bfloat16(v.x); o[1] = __float2bfloat16(v.y);
        o[2] = __float2bfloat16(v.z); o[3] = __float2bfloat16(v.w);
    }
}

// ---------------------------------------------------------------------------
extern "C" void kernel_launch(void* const* d_in, const int* in_sizes, int n_in,
                              void* d_out, int out_size, void* d_ws, size_t ws_size,
                              hipStream_t stream) {
    const float* x     = (const float*)d_in[0];
    const float* w1    = (const float*)d_in[1];
    const float* b1    = (const float*)d_in[2];
    const float* w2    = (const float*)d_in[3];
    const float* b2    = (const float*)d_in[4];
    const float* gamma = (const float*)d_in[5];
    const float* beta  = (const float*)d_in[6];
    const float* wc    = (const float*)d_in[7];
    float* out = (float*)d_out;

    char* ws = (char*)d_ws;
    size_t off = 0;
    auto alloc = [&](size_t bytes) -> void* {
        void* p = ws + off;
        off += (bytes + 255) & ~(size_t)255;
        return p;
    };

    __hip_bfloat16* xnb  = (__hip_bfloat16*)alloc((size_t)N_ROWS * DIM * 2);    // 32 MB (reused: h0)
    __hip_bfloat16* S    = (__hip_bfloat16*)alloc((size_t)N_ROWS * N_ROWS * 2); // 128 MB (reused: z1, z2b)
    double*         invn = (double*)alloc((size_t)N_ROWS * 8);
    int*            cand = (int*)alloc((size_t)N_ROWS * NCAND * 4);
    int*            idx6 = (int*)alloc((size_t)N_ROWS * KNN * 4);
    __hip_bfloat16* w1b  = (__hip_bfloat16*)alloc((size_t)DIM * DIM * 2);
    __hip_bfloat16* w2b  = (__hip_bfloat16*)alloc((size_t)DIM * DIM * 2);
    __hip_bfloat16* wcs  = (__hip_bfloat16*)alloc((size_t)NPAD * DIM * 2);
    float*          lb   = (float*)alloc((size_t)NPAD * 4);
    float*          stats = (float*)alloc((size_t)4 * DIM * 4);
    int*            wl   = (int*)alloc((size_t)N_ROWS * 4);
    int*            cnt  = (int*)alloc((size_t)256);

    __hip_bfloat16* h0  = xnb;                          // xn dead after syrk
    __hip_bfloat16* z1  = S;                            // S dead after topk
    __hip_bfloat16* z2b = S + (size_t)N_ROWS * DIM;     // next 32 MB of S region

    hipMemsetAsync(stats, 0, 2 * DIM * sizeof(float), stream);
    hipMemsetAsync(cnt, 0, sizeof(int), stream);

    normalize_kernel<<<N_ROWS, 256, 0, stream>>>(x, xnb, invn);
    f32_to_bf16_kernel<<<(DIM * DIM / 4) / 256, 256, 0, stream>>>(w1, w1b, DIM * DIM / 4);
    f32_to_bf16_kernel<<<(DIM * DIM / 4) / 256, 256, 0, stream>>>(w2, w2b, DIM * DIM / 4);

    // S = xn xn^T: 64 diagonal half-blocks (first) + 496 upper 256^2 tiles
    gemm_syrk<<<560, 512, 0, stream>>>(xnb, S);

    topk_cand_kernel<<<N_ROWS, 64, 0, stream>>>(S, cand, idx6, wl, cnt);
    rescore_kernel<<<N_ROWS, 256, 0, stream>>>(x, invn, cand, wl, cnt, idx6);
    aggregate_kernel<<<N_ROWS, 256, 0, stream>>>(x, idx6, h0);

    // z1 = relu(h0 @ w1^T + b1)   [bf16]
    gemm_nt_256<1><<<dim3(DIM / 256, N_ROWS / 256), 512, 0, stream>>>(
        h0, w1b, (void*)z1, b1, nullptr);
    // z2b = h@w2^T + b2 [bf16] with fused BN column stats
    gemm_nt_256<4><<<dim3(DIM / 256, N_ROWS / 256), 512, 0, stream>>>(
        z1, w2b, (void*)z2b, b2, stats);

    bn_finalize_kernel<<<DIM / 256, 256, 0, stream>>>(stats, gamma, beta);
    wc_fold_kernel<<<NPAD, 256, 0, stream>>>(wc, stats, wcs, lb);

    // logits = (z2*scale+shift) @ wc^T = z2b @ wcs^T + lb   [fp32, col<751]
    gemm_nt<5, 64><<<dim3(NPAD / 128, N_ROWS / 64), 256, 0, stream>>>(
        z2b, wcs, (void*)out, lb, nullptr, DIM, NCLS, NCLS);
}

// Round 3
// 700.149 us; speedup vs baseline: 1.0960x; 1.0178x over previous
//
#include <hip/hip_runtime.h>
#include <hip/hip_bf16.h>

// Problem constants
#define N_ROWS 8192
#define DIM    2048
#define NCLS   751
#define NPAD   768     // wc padded rows (6*128)
#define KNN    6       // K+1 neighbors (incl self)
#define NCAND  12      // rescore candidates (gap(6,12) >> bf16 quant error)
#define GAP_THRESH 1.25e-3f   // bf16 rank-6/7 gap above which top-6 set is exact

typedef __attribute__((ext_vector_type(8))) short bf16x8;
typedef __attribute__((ext_vector_type(4))) float f32x4;

// ---------------------------------------------------------------------------
// async global->LDS, 16B per lane. LDS dest must be wave-uniform base + lane*16.
__device__ __forceinline__ void async_ld16(const __hip_bfloat16* g, __hip_bfloat16* l) {
    __builtin_amdgcn_global_load_lds(
        (__attribute__((address_space(1))) void*)(g),
        (__attribute__((address_space(3))) void*)(l), 16, 0, 0);
}

__device__ __forceinline__ float bf16_to_f32(short s) {
    union { float f; unsigned u; } cv;
    cv.u = ((unsigned)(unsigned short)s) << 16;
    return cv.f;
}

// ---------------------------------------------------------------------------
// Row L2 norms (f64-accurate) + bf16 normalized rows for the similarity GEMM.
__global__ void normalize_kernel(const float* __restrict__ x,
                                 __hip_bfloat16* __restrict__ xnb,
                                 double* __restrict__ invnorm) {
    int row = blockIdx.x, tid = threadIdx.x;   // 256 threads
    const float4* xr4 = (const float4*)(x + (size_t)row * DIM);
    float4 v0 = xr4[tid], v1 = xr4[tid + 256];
    double s = (double)v0.x * v0.x + (double)v0.y * v0.y +
               (double)v0.z * v0.z + (double)v0.w * v0.w +
               (double)v1.x * v1.x + (double)v1.y * v1.y +
               (double)v1.z * v1.z + (double)v1.w * v1.w;
    __shared__ double red[256];
    red[tid] = s; __syncthreads();
    for (int off = 128; off; off >>= 1) {
        if (tid < off) red[tid] += red[tid + off];
        __syncthreads();
    }
    double norm = sqrt(red[0]);
    if (norm < 1e-12) norm = 1e-12;
    double inv = 1.0 / norm;
    if (tid == 0) invnorm[row] = inv;
    float invf = (float)inv;
    __hip_bfloat16* o0 = xnb + (size_t)row * DIM + tid * 4;
    o0[0] = __float2bfloat16(v0.x * invf);
    o0[1] = __float2bfloat16(v0.y * invf);
    o0[2] = __float2bfloat16(v0.z * invf);
    o0[3] = __float2bfloat16(v0.w * invf);
    __hip_bfloat16* o1 = o0 + 1024;
    o1[0] = __float2bfloat16(v1.x * invf);
    o1[1] = __float2bfloat16(v1.y * invf);
    o1[2] = __float2bfloat16(v1.z * invf);
    o1[3] = __float2bfloat16(v1.w * invf);
}

// ===========================================================================
// R3 tile engine: BM x 256 tile, BK=64, 8 waves (2Mx4N, per-wave BM/2 x 64),
// full-tile double-buffered LDS, 4 phases / K-step, ONLY 2 barriers / K-step.
// Key change vs R2: ds_reads for phase p+1 are issued right after phase p's
// MFMA cluster with NO hand-written lgkmcnt -- the compiler inserts
// fine-grained per-operand lgkm waits, so the LDS service of af1/b1 hides
// under the preceding MFMA cluster's drain. Only P0's 12-read burst (just
// after the close barrier) is exposed.
//   P0: read af0(8)+b0(4); stage B{0,1}; MFMA af0xb0 -> acc[m][n]
//       vmcnt(2) + barrier       (drains PREV A{j1,j3} -> af1 region valid)
//   P1: read af1(8); stage B{2,3}; MFMA af1xb0 -> acc[MI/2+m][n]
//   P2: read b1(4);  stage A{0,2}; MFMA af1xb1 -> acc[MI/2+m][2+n]
//   P3:              stage A{1,3}; MFMA af0xb1 -> acc[m][2+n]
//       vmcnt(2) + barrier       (drains all B + A{j0,j2}; A{j1,j3} in flight)
// FIFO ledger (per wave, BM=256, steady state):
//   at P0 tail: outstanding = prevA{1,3}(2) + B{0,1}(2) = 4 -> vmcnt(2) drains
//     prev A pair (rows 64-127/192-255 read by P1's af1). Barrier makes it
//     chip-wide.
//   at close:  outstanding = B(4) + A(4) = 8 -> vmcnt(2) drains B-all (next
//     P0's b0) + A{0,2} (rows 0-63/128-191 = next P0's af0). A{1,3} keeps
//     ~1 K-step of slack.
// BM=128 (diag halves): A staged in 2 row-interleaved passes pass0={0-31,
// 64-95}, pass1={32-63,96-127} so af0==pass0, af1==pass1 exactly; close
// vmcnt(1) leaves pass1 in flight, P0-tail vmcnt(2) drains it (3 outstanding
// there). LDS content layout identical to R2 (row-major), only the vmcnt
// batching of rows changed.
// Accumulation per element stays kt-ascending, s-ascending -> S bit-identical
// to R0/R1/R2.
// EPI: 0 = syrk store (direct + LDS-transposed)   1 = relu(v+bias)->bf16
//      4 = v+bias->bf16 + BN column stats
// ===========================================================================
template <int BM, int EPI>
__device__ __forceinline__ void tile_engine(
    const __hip_bfloat16* __restrict__ Aptr,
    const __hip_bfloat16* __restrict__ Bptr,
    char* __restrict__ smem,
    size_t bm, size_t bn,
    __hip_bfloat16* __restrict__ S,
    void* __restrict__ Cv,
    const float* __restrict__ bias,
    float* __restrict__ stats)
{
    constexpr int MI = BM / 32;                     // 8 or 4
    constexpr size_t ABYTES = (size_t)BM * 128;     // A tile bytes (BM x 64 bf16)
    constexpr size_t BUFS = ABYTES + 32768;         // + B tile (256 x 64 bf16)
    const int tid  = threadIdx.x;                   // 512 threads
    const int wave = tid >> 6, lane = tid & 63;
    const int wm = (wave >> 2) * (BM / 2), wn = (wave & 3) * 64;
    const int quad = lane >> 4, l15 = lane & 15;

    // staging: thread's fixed row/chunk within a 64-row pass
    const int srow = tid >> 3;                      // 0..63
    const int gsw  = ((tid & 7) ^ (srow & 7)) * 8;  // swizzled k-chunk (inverse of read)

    auto Asbuf = [&](int c) { return (__hip_bfloat16*)(smem + c * BUFS); };
    auto Bsbuf = [&](int c) { return (__hip_bfloat16*)(smem + c * BUFS + ABYTES); };

    // A stage pass p -> global/LDS row gr (BM=128: row-interleaved passes)
    auto arow = [&](int p) -> int {
        if constexpr (BM == 256) return (p << 6) + srow;
        else return (srow & 31) + ((srow >> 5) << 6) + (p << 5);
    };
    auto stageA = [&](__hip_bfloat16* Ad, int p, size_t kb) {
        int gr = arow(p);
        async_ld16(Aptr + (bm + gr) * (size_t)DIM + kb + gsw,
                   Ad + gr * 64 + (tid & 7) * 8);
    };
    auto stageB = [&](__hip_bfloat16* Bd, int j, size_t kb) {
        async_ld16(Bptr + (bn + (j << 6) + srow) * (size_t)DIM + kb + gsw,
                   Bd + (j << 12) + tid * 8);
    };

    f32x4 acc[MI][4];
#pragma unroll
    for (int mi = 0; mi < MI; ++mi)
#pragma unroll
        for (int ni = 0; ni < 4; ++ni)
            acc[mi][ni] = (f32x4){0.f, 0.f, 0.f, 0.f};

    constexpr int KT = DIM / 64;                    // 32 K-steps
    constexpr int VM_CLOSE = (BM == 256) ? 2 : 1;

    // ---- prologue: stage tile 0 into buf 0; LAST pass(es) = af1 rows
    {
        __hip_bfloat16* Ad = Asbuf(0);
        __hip_bfloat16* Bd = Bsbuf(0);
        stageB(Bd, 0, 0); stageB(Bd, 1, 0); stageB(Bd, 2, 0); stageB(Bd, 3, 0);
        if constexpr (BM == 256) {
            stageA(Ad, 0, 0); stageA(Ad, 2, 0);
            stageA(Ad, 1, 0); stageA(Ad, 3, 0);
            asm volatile("s_waitcnt vmcnt(2)" ::: "memory");
        } else {
            stageA(Ad, 0, 0);
            stageA(Ad, 1, 0);
            asm volatile("s_waitcnt vmcnt(1)" ::: "memory");
        }
        __builtin_amdgcn_s_barrier();
        __builtin_amdgcn_sched_barrier(0);
    }

#pragma unroll 1
    for (int kt = 0; kt < KT; ++kt) {
        const int cur = kt & 1;
        __hip_bfloat16* As = Asbuf(cur);
        __hip_bfloat16* Bs = Bsbuf(cur);
        __hip_bfloat16* An = Asbuf(cur ^ 1);
        __hip_bfloat16* Bn = Bsbuf(cur ^ 1);
        const bool st = (kt < KT - 1);
        const size_t kb = (size_t)(kt + 1) * 64;

        bf16x8 af0[2][MI / 2], af1[2][MI / 2], b0[2][2], b1[2][2];

        // ---------------- P0: read af0 + b0; stage B{0,1}; MFMA af0 x b0
#pragma unroll
        for (int s = 0; s < 2; ++s) {
#pragma unroll
            for (int m = 0; m < MI / 2; ++m) {
                int rr = wm + m * 16 + l15;
                af0[s][m] = *(const bf16x8*)&As[(rr * 8 + ((s * 4 + quad) ^ (rr & 7))) * 8];
            }
#pragma unroll
            for (int n = 0; n < 2; ++n) {
                int rr = wn + n * 16 + l15;
                b0[s][n] = *(const bf16x8*)&Bs[(rr * 8 + ((s * 4 + quad) ^ (rr & 7))) * 8];
            }
        }
        if (st) { stageB(Bn, 0, kb); stageB(Bn, 1, kb); }
        __builtin_amdgcn_s_setprio(1);
#pragma unroll
        for (int s = 0; s < 2; ++s)
#pragma unroll
            for (int m = 0; m < MI / 2; ++m)
#pragma unroll
                for (int n = 0; n < 2; ++n)
                    acc[m][n] = __builtin_amdgcn_mfma_f32_16x16x32_bf16(
                        af0[s][m], b0[s][n], acc[m][n], 0, 0, 0);
        __builtin_amdgcn_s_setprio(0);
        if (st) { asm volatile("s_waitcnt vmcnt(2)" ::: "memory"); }
        else    { asm volatile("s_waitcnt vmcnt(0)" ::: "memory"); }
        __builtin_amdgcn_s_barrier();
        __builtin_amdgcn_sched_barrier(0);

        // ---------------- P1: read af1; stage B{2,3}; MFMA af1 x b0
#pragma unroll
        for (int s = 0; s < 2; ++s)
#pragma unroll
            for (int m = 0; m < MI / 2; ++m) {
                int rr = wm + (BM / 4) + m * 16 + l15;
                af1[s][m] = *(const bf16x8*)&As[(rr * 8 + ((s * 4 + quad) ^ (rr & 7))) * 8];
            }
        if (st) { stageB(Bn, 2, kb); stageB(Bn, 3, kb); }
        __builtin_amdgcn_s_setprio(1);
#pragma unroll
        for (int s = 0; s < 2; ++s)
#pragma unroll
            for (int m = 0; m < MI / 2; ++m)
#pragma unroll
                for (int n = 0; n < 2; ++n)
                    acc[MI / 2 + m][n] = __builtin_amdgcn_mfma_f32_16x16x32_bf16(
                        af1[s][m], b0[s][n], acc[MI / 2 + m][n], 0, 0, 0);
        __builtin_amdgcn_s_setprio(0);

        // ---------------- P2: read b1; stage A{0,2}; MFMA af1 x b1
#pragma unroll
        for (int s = 0; s < 2; ++s)
#pragma unroll
            for (int n = 0; n < 2; ++n) {
                int rr = wn + 32 + n * 16 + l15;
                b1[s][n] = *(const bf16x8*)&Bs[(rr * 8 + ((s * 4 + quad) ^ (rr & 7))) * 8];
            }
        if (st) {
            if constexpr (BM == 256) { stageA(An, 0, kb); stageA(An, 2, kb); }
            else                     { stageA(An, 0, kb); }
        }
        __builtin_amdgcn_s_setprio(1);
#pragma unroll
        for (int s = 0; s < 2; ++s)
#pragma unroll
            for (int m = 0; m < MI / 2; ++m)
#pragma unroll
                for (int n = 0; n < 2; ++n)
                    acc[MI / 2 + m][2 + n] = __builtin_amdgcn_mfma_f32_16x16x32_bf16(
                        af1[s][m], b1[s][n], acc[MI / 2 + m][2 + n], 0, 0, 0);
        __builtin_amdgcn_s_setprio(0);

        // ---------------- P3: stage A{1,3}; MFMA af0 x b1; close
        if (st) {
            if constexpr (BM == 256) { stageA(An, 1, kb); stageA(An, 3, kb); }
            else                     { stageA(An, 1, kb); }
        }
        __builtin_amdgcn_s_setprio(1);
#pragma unroll
        for (int s = 0; s < 2; ++s)
#pragma unroll
            for (int m = 0; m < MI / 2; ++m)
#pragma unroll
                for (int n = 0; n < 2; ++n)
                    acc[m][2 + n] = __builtin_amdgcn_mfma_f32_16x16x32_bf16(
                        af0[s][m], b1[s][n], acc[m][2 + n], 0, 0, 0);
        __builtin_amdgcn_s_setprio(0);
        if (st) {
            if constexpr (BM == 256) { asm volatile("s_waitcnt vmcnt(2)" ::: "memory"); }
            else                     { asm volatile("s_waitcnt vmcnt(1)" ::: "memory"); }
        } else {
            asm volatile("s_waitcnt vmcnt(0)" ::: "memory");
        }
        __builtin_amdgcn_s_barrier();
        __builtin_amdgcn_sched_barrier(0);
    }

    // ---------------- epilogues
    if constexpr (EPI == 0) {
        // direct store (C/D layout: col=lane&15, row=quad*4+e)
#pragma unroll
        for (int mi = 0; mi < MI; ++mi)
#pragma unroll
            for (int ni = 0; ni < 4; ++ni)
#pragma unroll
                for (int e = 0; e < 4; ++e) {
                    size_t row = bm + wm + mi * 16 + quad * 4 + e;
                    size_t col = bn + wn + ni * 16 + l15;
                    S[row * N_ROWS + col] = __float2bfloat16(acc[mi][ni][e]);
                }
        // transposed tile via LDS (8 passes of 32 cols), vector stores
        __hip_bfloat16* T = (__hip_bfloat16*)smem;
        constexpr int TSTR = BM + 8;
#pragma unroll
        for (int p = 0; p < 8; ++p) {
            __syncthreads();
            if ((wave & 3) == (p >> 1)) {
#pragma unroll
                for (int nio = 0; nio < 2; ++nio) {
                    const int ni = (p & 1) * 2 + nio;
                    const int tc = ni * 16 + l15 - (p & 1) * 32;   // 0..31
#pragma unroll
                    for (int mi = 0; mi < MI; ++mi)
#pragma unroll
                        for (int e = 0; e < 4; ++e) {
                            int r = wm + mi * 16 + quad * 4 + e;
                            T[tc * TSTR + r] = __float2bfloat16(acc[mi][ni][e]);
                        }
                }
            }
            __syncthreads();
#pragma unroll
            for (int j2 = 0; j2 < BM / 128; ++j2) {
                int q = tid + 512 * j2;
                int tc = q / (BM / 8), r8 = (q % (BM / 8)) * 8;
                *(bf16x8*)&S[(bn + p * 32 + tc) * (size_t)N_ROWS + bm + r8] =
                    *(const bf16x8*)&T[tc * TSTR + r8];
            }
        }
    } else {
        float s1[4] = {0.f, 0.f, 0.f, 0.f}, s2[4] = {0.f, 0.f, 0.f, 0.f};
#pragma unroll
        for (int mi = 0; mi < MI; ++mi)
#pragma unroll
            for (int ni = 0; ni < 4; ++ni)
#pragma unroll
                for (int e = 0; e < 4; ++e) {
                    size_t row = bm + wm + mi * 16 + quad * 4 + e;
                    int col = (int)(bn + wn + ni * 16 + l15);
                    float v = acc[mi][ni][e] + bias[col];
                    if constexpr (EPI == 1) v = v > 0.f ? v : 0.f;
                    ((__hip_bfloat16*)Cv)[row * (size_t)DIM + col] = __float2bfloat16(v);
                    if constexpr (EPI == 4) { s1[ni] += v; s2[ni] += v * v; }
                }
        if constexpr (EPI == 4) {
            __syncthreads();
            float* sred = (float*)smem;     // [2 M-halves][256 cols][2 stats]
#pragma unroll
            for (int ni = 0; ni < 4; ++ni) {
                float a = s1[ni], bq = s2[ni];
                a += __shfl_xor(a, 16);  a += __shfl_xor(a, 32);
                bq += __shfl_xor(bq, 16); bq += __shfl_xor(bq, 32);
                if (lane < 16) {
                    int c = wn + ni * 16 + l15;
                    sred[((wave >> 2) * 256 + c) * 2 + 0] = a;
                    sred[((wave >> 2) * 256 + c) * 2 + 1] = bq;
                }
            }
            __syncthreads();
            if (tid < 256) {
                float ta = sred[tid * 2] + sred[(256 + tid) * 2];
                float tb = sred[tid * 2 + 1] + sred[(256 + tid) * 2 + 1];
                atomicAdd(&stats[bn + tid], ta);
                atomicAdd(&stats[DIM + bn + tid], tb);
            }
        }
    }
}

// ---------------------------------------------------------------------------
// Triangular symmetric GEMM via tile_engine. Grid = 560 blocks:
//   b in [0,64):  diagonal half-blocks 128x256 (spread mod 8 over XCDs)
//   b in [64,560): strict upper-triangle 256x256 tiles (496 = 8 x 62),
//     XCD-chunked: XCD x gets fulls [62x, 62x+62) -- a contiguous run of the
//     triangular order, so the shared A-panel (bi) stays hot in that XCD's L2
//     (T1; 560 % 8 == 0, balanced 66 T-units per XCD).
// Every block writes its tile directly AND transposed; diagonal overlaps are
// idempotent (symmetric values, identical bytes).
__global__ __launch_bounds__(512, 2)
void gemm_syrk(const __hip_bfloat16* __restrict__ A,
               __hip_bfloat16* __restrict__ S) {
    __shared__ __align__(16) char smem[2 * (256 * 128 + 32768)];   // 128 KB
    int b = blockIdx.x;
    if (b < 64) {
        int ti = b >> 1, half = b & 1;
        tile_engine<128, 0>(A, A, smem,
                            (size_t)ti * 256 + (size_t)half * 128,
                            (size_t)ti * 256, S, nullptr, nullptr, nullptr);
    } else {
        int o = b - 64;
        int f = (o & 7) * 62 + (o >> 3);   // XCD-contiguous chunk of 496 fulls
        int bi = (int)((63.0 - sqrt(3969.0 - 8.0 * (double)f)) * 0.5);
        while (31 * (bi + 1) - (bi + 1) * bi / 2 <= f) ++bi;
        while (bi > 0 && 31 * bi - bi * (bi - 1) / 2 > f) --bi;
        int bj = bi + 1 + (f - (31 * bi - bi * (bi - 1) / 2));
        tile_engine<256, 0>(A, A, smem, (size_t)bi * 256, (size_t)bj * 256,
                            S, nullptr, nullptr, nullptr);
    }
}

// ---------------------------------------------------------------------------
// 256x256 NT GEMM via tile_engine (grid (DIM/256, N_ROWS/256) = 256 blocks =
// exactly 1 block/CU, no tail; x-fastest dispatch already gives per-XCD
// B-panel locality). EPI 1/4 as before.
template <int EPI>
__global__ __launch_bounds__(512, 2)
void gemm_nt_256(const __hip_bfloat16* __restrict__ A,
                 const __hip_bfloat16* __restrict__ B,
                 void* __restrict__ Cv,
                 const float* __restrict__ bias,
                 float* __restrict__ stats) {
    __shared__ __align__(16) char smem[2 * (256 * 128 + 32768)];   // 128 KB
    tile_engine<256, EPI>(A, B, smem,
                          (size_t)blockIdx.y * 256, (size_t)blockIdx.x * 256,
                          nullptr, Cv, bias, stats);
}

// ---------------------------------------------------------------------------
// Generic NT bf16 GEMM, BK=64 (kept for the classifier: EPI 5, TM=64).
template <int EPI, int TM>
__global__ __launch_bounds__(256)
void gemm_nt(const __hip_bfloat16* __restrict__ A,
             const __hip_bfloat16* __restrict__ B,
             void* __restrict__ Cv,
             const float* __restrict__ bias,
             float* __restrict__ stats,
             int K, int ldc, int ncols) {
    constexpr int MI = TM / 32;                       // 4 or 2
    __shared__ __align__(16) char smem[TM * 128 + 16384];
    __hip_bfloat16* As = (__hip_bfloat16*)smem;                // TM x 64
    __hip_bfloat16* Bs = (__hip_bfloat16*)(smem + TM * 128);   // 128 x 64
    const int tid  = threadIdx.x;
    const size_t bm = (size_t)blockIdx.y * TM, bn = (size_t)blockIdx.x * 128;
    const int wave = tid >> 6, lane = tid & 63;
    const int wm = (wave & 1) * (TM / 2), wn = (wave >> 1) * 64;
    const int quad = lane >> 4, l15 = lane & 15;

    f32x4 acc[MI][4];
#pragma unroll
    for (int mi = 0; mi < MI; ++mi)
#pragma unroll
        for (int ni = 0; ni < 4; ++ni)
            acc[mi][ni] = (f32x4){0.f, 0.f, 0.f, 0.f};

    const int KT = K >> 6;
    for (int kt = 0; kt < KT; ++kt) {
        const int kb = kt << 6;
        __syncthreads();
#pragma unroll
        for (int j = 0; j < TM / 32; ++j) {
            int q = tid + 256 * j, r = q >> 3, g = ((q & 7) ^ (r & 7)) * 8;
            async_ld16(A + (bm + r) * (size_t)K + kb + g, As + q * 8);
        }
#pragma unroll
        for (int j = 0; j < 4; ++j) {
            int q = tid + 256 * j, r = q >> 3, g = ((q & 7) ^ (r & 7)) * 8;
            async_ld16(B + (bn + r) * (size_t)K + kb + g, Bs + q * 8);
        }
        __syncthreads();

#pragma unroll
        for (int s = 0; s < 2; ++s) {
            bf16x8 af[MI], bfr[4];
#pragma unroll
            for (int mi = 0; mi < MI; ++mi) {
                int rr = wm + mi * 16 + l15;
                af[mi] = *(const bf16x8*)&As[(rr * 8 + ((s * 4 + quad) ^ (rr & 7))) * 8];
            }
#pragma unroll
            for (int ni = 0; ni < 4; ++ni) {
                int rr = wn + ni * 16 + l15;
                bfr[ni] = *(const bf16x8*)&Bs[(rr * 8 + ((s * 4 + quad) ^ (rr & 7))) * 8];
            }
#pragma unroll
            for (int mi = 0; mi < MI; ++mi)
#pragma unroll
                for (int ni = 0; ni < 4; ++ni)
                    acc[mi][ni] = __builtin_amdgcn_mfma_f32_16x16x32_bf16(
                        af[mi], bfr[ni], acc[mi][ni], 0, 0, 0);
        }
    }

#pragma unroll
    for (int mi = 0; mi < MI; ++mi)
#pragma unroll
        for (int ni = 0; ni < 4; ++ni)
#pragma unroll
            for (int e = 0; e < 4; ++e) {
                size_t row = bm + wm + mi * 16 + quad * 4 + e;
                int col = (int)(bn + wn + ni * 16 + l15);
                float v = acc[mi][ni][e];
                v += bias[col];
                if (col < ncols)
                    ((float*)Cv)[row * (size_t)ldc + col] = v;
            }
}

// ---------------------------------------------------------------------------
// Per-row top-NCAND candidates from bf16 similarity row. 1 wave per row.
__global__ void topk_cand_kernel(const __hip_bfloat16* __restrict__ S,
                                 int* __restrict__ cand,
                                 int* __restrict__ idx6,
                                 int* __restrict__ wl,
                                 int* __restrict__ cnt) {
    int row = blockIdx.x, lane = threadIdx.x;   // 64 threads
    const bf16x8* Sr8 = (const bf16x8*)(S + (size_t)row * N_ROWS);
    float bv[6]; int bi6[6];
#pragma unroll
    for (int t = 0; t < 6; ++t) { bv[t] = -1e30f; bi6[t] = -1; }
    float vmin = -1e30f;
    for (int it = 0; it < N_ROWS / (64 * 8); ++it) {
        int c8 = it * 64 + lane;
        bf16x8 v8 = Sr8[c8];
#pragma unroll
        for (int u = 0; u < 8; ++u) {
            float v = bf16_to_f32(v8[u]);
            if (v > vmin) {
                int ms = 0; float mv = bv[0];
#pragma unroll
                for (int t = 1; t < 6; ++t) if (bv[t] < mv) { mv = bv[t]; ms = t; }
                bv[ms] = v; bi6[ms] = c8 * 8 + u;
                vmin = bv[0];
#pragma unroll
                for (int t = 1; t < 6; ++t) vmin = fminf(vmin, bv[t]);
            }
        }
    }
    __shared__ float sv[384];
    __shared__ int   si[384];
    __shared__ float topv[NCAND];
    __shared__ int   topi[NCAND];
#pragma unroll
    for (int t = 0; t < 6; ++t) { sv[lane * 6 + t] = bv[t]; si[lane * 6 + t] = bi6[t]; }
    __syncthreads();
    for (int t = 0; t < NCAND; ++t) {
        float m = -1e30f; int mpos = -1, midx = 0x7fffffff;
        for (int e = lane; e < 384; e += 64) {
            float v = sv[e]; int ix = si[e];
            if (v > m || (v == m && ix < midx)) { m = v; mpos = e; midx = ix; }
        }
#pragma unroll
        for (int off = 32; off; off >>= 1) {
            float ov = __shfl_xor(m, off);
            int   op = __shfl_xor(mpos, off);
            int   oi = __shfl_xor(midx, off);
            if (ov > m || (ov == m && oi < midx)) { m = ov; mpos = op; midx = oi; }
        }
        if (lane == 0) {
            cand[row * NCAND + t] = midx;
            topv[t] = m; topi[t] = midx;
            sv[mpos] = -1e30f;
        }
        __syncthreads();
    }
    if (lane == 0) {
        if (topv[KNN - 1] - topv[KNN] >= GAP_THRESH) {
#pragma unroll
            for (int t = 0; t < KNN; ++t) idx6[row * KNN + t] = topi[t];
        } else {
            int p = atomicAdd(cnt, 1);
            wl[p] = row;
        }
    }
}

// ---------------------------------------------------------------------------
// Exact (f64) rescore of ambiguous rows only (worklist-driven).
__global__ void rescore_kernel(const float* __restrict__ x,
                               const double* __restrict__ invnorm,
                               const int* __restrict__ cand,
                               const int* __restrict__ wl,
                               const int* __restrict__ cnt,
                               int* __restrict__ idx6) {
    if (blockIdx.x >= *cnt) return;          // uniform per block
    int row = wl[blockIdx.x];
    int tid = threadIdx.x;                   // 256 threads
    int wave = tid >> 6, lane = tid & 63;
    __shared__ float4 xi4[DIM / 4];
    __shared__ double simv[NCAND];
    __shared__ int    cnd[NCAND];
    const float4* xr4 = (const float4*)(x + (size_t)row * DIM);
    xi4[tid] = xr4[tid]; xi4[tid + 256] = xr4[tid + 256];
    if (tid < NCAND) cnd[tid] = cand[row * NCAND + tid];
    __syncthreads();
    for (int t = wave; t < NCAND; t += 4) {
        int j = cnd[t];
        if (j == row) { if (lane == 0) simv[t] = 1e30; continue; }  // self: rank 1
        const float4* xj4 = (const float4*)(x + (size_t)j * DIM);
        double s = 0.0;
        for (int k = lane; k < DIM / 4; k += 64) {
            float4 a = xj4[k], bq = xi4[k];
            s += (double)a.x * bq.x + (double)a.y * bq.y +
                 (double)a.z * bq.z + (double)a.w * bq.w;
        }
#pragma unroll
        for (int off = 32; off; off >>= 1) s += __shfl_xor(s, off);
        if (lane == 0) simv[t] = s * invnorm[row] * invnorm[j];
    }
    __syncthreads();
    if (tid == 0) {
        double vals[NCAND]; int idxs[NCAND];
        for (int t = 0; t < NCAND; ++t) { vals[t] = simv[t]; idxs[t] = cnd[t]; }
        for (int t = 0; t < KNN; ++t) {
            int best = 0; double bvv = -1e300; int bji = 0x7fffffff;
            for (int e = 0; e < NCAND; ++e) {
                if (vals[e] > bvv || (vals[e] == bvv && idxs[e] < bji)) {
                    bvv = vals[e]; best = e; bji = idxs[e];
                }
            }
            idx6[row * KNN + t] = idxs[best];
            vals[best] = -1e300;
        }
    }
}

// ---------------------------------------------------------------------------
// GIN aggregation with reciprocal mask: h0 = 1.3*x_i + sum reciprocal x_j -> bf16
__global__ void aggregate_kernel(const float* __restrict__ x,
                                 const int* __restrict__ idx6,
                                 __hip_bfloat16* __restrict__ h0) {
    int row = blockIdx.x, tid = threadIdx.x;   // 256 threads
    __shared__ int nb[KNN];
    __shared__ int fl[KNN];
    if (tid < KNN) {
        int j = idx6[row * KNN + tid];
        nb[tid] = j;
        int f = 0;
        for (int t = 0; t < KNN; ++t) if (idx6[j * KNN + t] == row) f = 1;
        fl[tid] = f;
    }
    __syncthreads();
    int f0 = tid * 8;
    const float4* xr4 = (const float4*)(x + (size_t)row * DIM + f0);
    float4 a0 = xr4[0], a1 = xr4[1];
    float acc[8] = {1.3f * a0.x, 1.3f * a0.y, 1.3f * a0.z, 1.3f * a0.w,
                    1.3f * a1.x, 1.3f * a1.y, 1.3f * a1.z, 1.3f * a1.w};
    for (int t = 0; t < KNN; ++t) {
        if (fl[t]) {
            const float4* xj4 = (const float4*)(x + (size_t)nb[t] * DIM + f0);
            float4 b0 = xj4[0], b1 = xj4[1];
            acc[0] += b0.x; acc[1] += b0.y; acc[2] += b0.z; acc[3] += b0.w;
            acc[4] += b1.x; acc[5] += b1.y; acc[6] += b1.z; acc[7] += b1.w;
        }
    }
#pragma unroll
    for (int u = 0; u < 8; ++u)
        h0[(size_t)row * DIM + f0 + u] = __float2bfloat16(acc[u]);
}

// ---------------------------------------------------------------------------
__global__ void bn_finalize_kernel(float* __restrict__ stats,
                                   const float* __restrict__ gamma,
                                   const float* __restrict__ beta) {
    int c = blockIdx.x * 256 + threadIdx.x;         // 2048
    float mean = stats[c] * (1.0f / 8192.0f);
    float var  = stats[DIM + c] * (1.0f / 8192.0f) - mean * mean;
    float sc   = gamma[c] / sqrtf(var + 1e-5f);
    stats[2 * DIM + c] = sc;                        // scale
    stats[3 * DIM + c] = beta[c] - mean * sc;       // shift
}

// Fold BN into classifier: wcs[c,k] = wc[c,k]*scale[k] (bf16, zero-padded rows),
// lb[c] = sum_k shift[k]*wc[c,k].
__global__ void wc_fold_kernel(const float* __restrict__ wc,
                               const float* __restrict__ stats,
                               __hip_bfloat16* __restrict__ wcs,
                               float* __restrict__ lb) {
    int r = blockIdx.x, tid = threadIdx.x;          // 768 blocks x 256
    int k0 = tid * 8;
    float part = 0.f;
    if (r < NCLS) {
#pragma unroll
        for (int u = 0; u < 8; ++u) {
            int k = k0 + u;
            float w = wc[(size_t)r * DIM + k];
            wcs[(size_t)r * DIM + k] = __float2bfloat16(w * stats[2 * DIM + k]);
            part += w * stats[3 * DIM + k];
        }
    } else {
#pragma unroll
        for (int u = 0; u < 8; ++u)
            wcs[(size_t)r * DIM + k0 + u] = __float2bfloat16(0.f);
    }
    __shared__ float red[256];
    red[tid] = part; __syncthreads();
    for (int off = 128; off; off >>= 1) {
        if (tid < off) red[tid] += red[tid + off];
        __syncthreads();
    }
    if (tid == 0) lb[r] = red[0];
}

// ---------------------------------------------------------------------------
__global__ void f32_to_bf16_kernel(const float* __restrict__ src,
                                   __hip_bfloat16* __restrict__ dst, int n4) {
    int i = blockIdx.x * 256 + threadIdx.x;
    if (i < n4) {
        float4 v = ((const float4*)src)[i];
        __hip_bfloat16* o = dst + (size_t)i * 4;
        o[0] = __float2bfloat16(v.x); o[1] = __float2bfloat16(v.y);
        o[2] = __float2bfloat16(v.z); o[3] = __float2bfloat16(v.w);
    }
}

// ---------------------------------------------------------------------------
extern "C" void kernel_launch(void* const* d_in, const int* in_sizes, int n_in,
                              void* d_out, int out_size, void* d_ws, size_t ws_size,
                              hipStream_t stream) {
    const float* x     = (const float*)d_in[0];
    const float* w1    = (const float*)d_in[1];
    const float* b1    = (const float*)d_in[2];
    const float* w2    = (const float*)d_in[3];
    const float* b2    = (const float*)d_in[4];
    const float* gamma = (const float*)d_in[5];
    const float* beta  = (const float*)d_in[6];
    const float* wc    = (const float*)d_in[7];
    float* out = (float*)d_out;

    char* ws = (char*)d_ws;
    size_t off = 0;
    auto alloc = [&](size_t bytes) -> void* {
        void* p = ws + off;
        off += (bytes + 255) & ~(size_t)255;
        return p;
    };

    __hip_bfloat16* xnb  = (__hip_bfloat16*)alloc((size_t)N_ROWS * DIM * 2);    // 32 MB (reused: h0)
    __hip_bfloat16* S    = (__hip_bfloat16*)alloc((size_t)N_ROWS * N_ROWS * 2); // 128 MB (reused: z1, z2b)
    double*         invn = (double*)alloc((size_t)N_ROWS * 8);
    int*            cand = (int*)alloc((size_t)N_ROWS * NCAND * 4);
    int*            idx6 = (int*)alloc((size_t)N_ROWS * KNN * 4);
    __hip_bfloat16* w1b  = (__hip_bfloat16*)alloc((size_t)DIM * DIM * 2);
    __hip_bfloat16* w2b  = (__hip_bfloat16*)alloc((size_t)DIM * DIM * 2);
    __hip_bfloat16* wcs  = (__hip_bfloat16*)alloc((size_t)NPAD * DIM * 2);
    float*          lb   = (float*)alloc((size_t)NPAD * 4);
    float*          stats = (float*)alloc((size_t)4 * DIM * 4);
    int*            wl   = (int*)alloc((size_t)N_ROWS * 4);
    int*            cnt  = (int*)alloc((size_t)256);

    __hip_bfloat16* h0  = xnb;                          // xn dead after syrk
    __hip_bfloat16* z1  = S;                            // S dead after topk
    __hip_bfloat16* z2b = S + (size_t)N_ROWS * DIM;     // next 32 MB of S region

    hipMemsetAsync(stats, 0, 2 * DIM * sizeof(float), stream);
    hipMemsetAsync(cnt, 0, sizeof(int), stream);

    normalize_kernel<<<N_ROWS, 256, 0, stream>>>(x, xnb, invn);
    f32_to_bf16_kernel<<<(DIM * DIM / 4) / 256, 256, 0, stream>>>(w1, w1b, DIM * DIM / 4);
    f32_to_bf16_kernel<<<(DIM * DIM / 4) / 256, 256, 0, stream>>>(w2, w2b, DIM * DIM / 4);

    // S = xn xn^T: 64 diagonal half-blocks + 496 upper 256^2 tiles (XCD-chunked)
    gemm_syrk<<<560, 512, 0, stream>>>(xnb, S);

    topk_cand_kernel<<<N_ROWS, 64, 0, stream>>>(S, cand, idx6, wl, cnt);
    rescore_kernel<<<N_ROWS, 256, 0, stream>>>(x, invn, cand, wl, cnt, idx6);
    aggregate_kernel<<<N_ROWS, 256, 0, stream>>>(x, idx6, h0);

    // z1 = relu(h0 @ w1^T + b1)   [bf16]
    gemm_nt_256<1><<<dim3(DIM / 256, N_ROWS / 256), 512, 0, stream>>>(
        h0, w1b, (void*)z1, b1, nullptr);
    // z2b = h@w2^T + b2 [bf16] with fused BN column stats
    gemm_nt_256<4><<<dim3(DIM / 256, N_ROWS / 256), 512, 0, stream>>>(
        z1, w2b, (void*)z2b, b2, stats);

    bn_finalize_kernel<<<DIM / 256, 256, 0, stream>>>(stats, gamma, beta);
    wc_fold_kernel<<<NPAD, 256, 0, stream>>>(wc, stats, wcs, lb);

    // logits = (z2*scale+shift) @ wc^T = z2b @ wcs^T + lb   [fp32, col<751]
    gemm_nt<5, 64><<<dim3(NPAD / 128, N_ROWS / 64), 256, 0, stream>>>(
        z2b, wcs, (void*)out, lb, nullptr, DIM, NCLS, NCLS);
}